// Round 2
// baseline (1610.880 us; speedup 1.0000x reference)
//
#include <hip/hip_runtime.h>
#include <math.h>

#define D_MODEL 384
#define D_INNER 768
#define D_STATE 16
#define DT_RANK 24
#define NTOK    2048
#define XDIM    56    // DT_RANK + 2*D_STATE
#define CHUNK   64
#define NCHUNK  (NTOK / CHUNK)   // 32

// ---------- ordering maps: sequence position p -> canonical token (l*256+h*16+w)
__device__ __forceinline__ int tok_of(int order, int p) {
    int q = (order & 1) ? (NTOK - 1 - p) : p;
    int grp = order >> 1;          // 0: HWL, 1: LWH, 2: LHW (canonical)
    int l, h, w;
    if (grp == 0)      { h = q >> 7;  w = (q >> 3) & 15; l = q & 7;  }
    else if (grp == 1) { l = q >> 8;  w = (q >> 4) & 15; h = q & 15; }
    else               { return q; }
    return l * 256 + h * 16 + w;
}

__device__ __forceinline__ float sigmoidf_(float x) { return 1.f / (1.f + expf(-x)); }
__device__ __forceinline__ float softplusf_(float x) { return (x > 20.f) ? x : log1pf(expf(x)); }

// ---------- RMSNorm with gather from canonical residual into sequence order
__global__ __launch_bounds__(128) void rmsnorm_gather_k(
    const float* __restrict__ R, const float* __restrict__ nw,
    float* __restrict__ Xn, int order)
{
    const int p   = blockIdx.x;
    const int tok = tok_of(order, p);
    const float* src = R + (size_t)tok * D_MODEL;
    const int tid = threadIdx.x;
    float v0 = src[tid], v1 = src[tid + 128], v2 = src[tid + 256];
    float ss = v0 * v0 + v1 * v1 + v2 * v2;
#pragma unroll
    for (int off = 32; off > 0; off >>= 1) ss += __shfl_xor(ss, off);
    __shared__ float tot[2];
    if ((tid & 63) == 0) tot[tid >> 6] = ss;
    __syncthreads();
    const float rs = rsqrtf((tot[0] + tot[1]) * (1.f / D_MODEL) + 1e-5f);
    float* dst = Xn + (size_t)p * D_MODEL;
    dst[tid]       = v0 * rs * nw[tid];
    dst[tid + 128] = v1 * rs * nw[tid + 128];
    dst[tid + 256] = v2 * rs * nw[tid + 256];
}

// ---------- generic tiled fp32 GEMM: C[M,N] = A[M,K(lda)] * W[N,K]^T
// MODE 0: plain store. MODE 1: softplus(acc + bias[col]). MODE 2: R[tok(row)*N+col] += acc.
template<int MODE>
__global__ __launch_bounds__(256, 2) void gemm_k(
    const float* __restrict__ A, int lda,
    const float* __restrict__ W,
    float* __restrict__ C,
    int M, int N, int K,
    const float* __restrict__ bias,
    int order)
{
    __shared__ float As[16][68];   // [k][m], pad 68 -> <=2-way bank aliasing (free)
    __shared__ float Ws[16][68];   // [k][n]
    const int tid = threadIdx.x;
    const int m0 = blockIdx.y * 64;
    const int n0 = blockIdx.x * 64;
    const int tx = tid & 15, ty = tid >> 4;
    const int lrow = tid >> 2;          // 0..63
    const int lk   = (tid & 3) << 2;    // 0,4,8,12
    float acc[4][4] = {{0.f}};

    for (int k0 = 0; k0 < K; k0 += 16) {
        {
            const int m = m0 + lrow;
            const float* src = A + (size_t)m * lda + (k0 + lk);
            float4 v = make_float4(0.f, 0.f, 0.f, 0.f);
            if (k0 + lk + 3 < K) v = *(const float4*)src;
            else {
                if (k0 + lk + 0 < K) v.x = src[0];
                if (k0 + lk + 1 < K) v.y = src[1];
                if (k0 + lk + 2 < K) v.z = src[2];
            }
            As[lk + 0][lrow] = v.x; As[lk + 1][lrow] = v.y;
            As[lk + 2][lrow] = v.z; As[lk + 3][lrow] = v.w;

            const int n = n0 + lrow;
            float4 u = make_float4(0.f, 0.f, 0.f, 0.f);
            if (n < N) {
                const float* srcw = W + (size_t)n * K + (k0 + lk);
                if (k0 + lk + 3 < K) u = *(const float4*)srcw;
                else {
                    if (k0 + lk + 0 < K) u.x = srcw[0];
                    if (k0 + lk + 1 < K) u.y = srcw[1];
                    if (k0 + lk + 2 < K) u.z = srcw[2];
                }
            }
            Ws[lk + 0][lrow] = u.x; Ws[lk + 1][lrow] = u.y;
            Ws[lk + 2][lrow] = u.z; Ws[lk + 3][lrow] = u.w;
        }
        __syncthreads();
#pragma unroll
        for (int k = 0; k < 16; ++k) {
            float4 a4 = *(const float4*)&As[k][ty * 4];
            float4 w4 = *(const float4*)&Ws[k][tx * 4];
            float ar[4] = {a4.x, a4.y, a4.z, a4.w};
            float wr[4] = {w4.x, w4.y, w4.z, w4.w};
#pragma unroll
            for (int i = 0; i < 4; ++i)
#pragma unroll
                for (int j = 0; j < 4; ++j)
                    acc[i][j] = fmaf(ar[i], wr[j], acc[i][j]);
        }
        __syncthreads();
    }

#pragma unroll
    for (int i = 0; i < 4; ++i) {
        const int row  = m0 + ty * 4 + i;
        const int col0 = n0 + tx * 4;
        if (MODE == 0) {
            if (col0 + 3 < N) {
                float4 v = make_float4(acc[i][0], acc[i][1], acc[i][2], acc[i][3]);
                *(float4*)&C[(size_t)row * N + col0] = v;
            } else {
#pragma unroll
                for (int j = 0; j < 4; ++j)
                    if (col0 + j < N) C[(size_t)row * N + col0 + j] = acc[i][j];
            }
        } else if (MODE == 1) {
#pragma unroll
            for (int j = 0; j < 4; ++j) {
                const int col = col0 + j;
                if (col < N) C[(size_t)row * N + col] = softplusf_(acc[i][j] + bias[col]);
            }
        } else {
            const int tok = tok_of(order, row);
            float4* dst = (float4*)&C[(size_t)tok * N + col0];
            float4 r = *dst;
            r.x += acc[i][0]; r.y += acc[i][1]; r.z += acc[i][2]; r.w += acc[i][3];
            *dst = r;
        }
    }
}

// ---------- causal depthwise conv (k=4) + SiLU; xp = XZ[:, 0:768]
__global__ __launch_bounds__(256) void conv_silu_k(
    const float* __restrict__ XZ, const float* __restrict__ cw,
    const float* __restrict__ cb, float* __restrict__ XC)
{
    const int idx = blockIdx.x * 256 + threadIdx.x;   // p*768 + c
    const int c = idx % D_INNER;
    const int p = idx / D_INNER;
    float acc = cb[c];
#pragma unroll
    for (int k = 0; k < 4; ++k) {
        const int pp = p - 3 + k;
        if (pp >= 0) acc = fmaf(cw[c * 4 + k], XZ[(size_t)pp * (2 * D_INNER) + c], acc);
    }
    XC[idx] = acc * sigmoidf_(acc);
}

// ---------- chunked selective scan, phase 1: per-chunk (prod a, partial h) from h=0
__global__ __launch_bounds__(256) void scan_phase1_k(
    const float* __restrict__ XC, const float* __restrict__ DT,
    const float* __restrict__ XD, const float* __restrict__ A_log,
    float* __restrict__ Aprod, float* __restrict__ Hpart)
{
    const int tid = threadIdx.x;
    const int s = tid & 15;
    const int d = blockIdx.x * 16 + (tid >> 4);
    const int chunk = blockIdx.y;
    const float Aneg = -expf(A_log[d * D_STATE + s]);
    float h = 0.f, ap = 1.f;
    const int t0 = chunk * CHUNK;
#pragma unroll 4
    for (int t = t0; t < t0 + CHUNK; ++t) {
        const float dt = DT[(size_t)t * D_INNER + d];
        const float u  = XC[(size_t)t * D_INNER + d];
        const float Bv = XD[(size_t)t * XDIM + DT_RANK + s];
        const float a  = expf(dt * Aneg);
        h = fmaf(a, h, dt * Bv * u);
        ap *= a;
    }
    const int idx = (chunk * D_INNER + d) * D_STATE + s;
    Aprod[idx] = ap;
    Hpart[idx] = h;
}

// ---------- phase 2: sequential scan over chunk summaries -> per-chunk initial h
__global__ __launch_bounds__(256) void scan_phase2_k(
    const float* __restrict__ Aprod, const float* __restrict__ Hpart,
    float* __restrict__ Hinit)
{
    const int tid = blockIdx.x * 256 + threadIdx.x;   // d*16+s, 12288 total
    float h = 0.f;
#pragma unroll
    for (int c = 0; c < NCHUNK; ++c) {
        const int idx = c * (D_INNER * D_STATE) + tid;
        Hinit[idx] = h;
        h = fmaf(Aprod[idx], h, Hpart[idx]);
    }
}

// ---------- phase 3: recompute within chunk from correct h0; fused u*D + gate*silu(z)
__global__ __launch_bounds__(256) void scan_phase3_k(
    const float* __restrict__ XC, const float* __restrict__ DT,
    const float* __restrict__ XD, const float* __restrict__ XZ,
    const float* __restrict__ A_log, const float* __restrict__ Dp,
    const float* __restrict__ Hinit, float* __restrict__ YG)
{
    const int tid = threadIdx.x;
    const int s = tid & 15;
    const int d = blockIdx.x * 16 + (tid >> 4);
    const int chunk = blockIdx.y;
    const float Aneg = -expf(A_log[d * D_STATE + s]);
    const float Dv = Dp[d];
    float h = Hinit[(chunk * D_INNER + d) * D_STATE + s];
    const int t0 = chunk * CHUNK;
#pragma unroll 4
    for (int t = t0; t < t0 + CHUNK; ++t) {
        const float dt = DT[(size_t)t * D_INNER + d];
        const float u  = XC[(size_t)t * D_INNER + d];
        const float Bv = XD[(size_t)t * XDIM + DT_RANK + s];
        const float Cv = XD[(size_t)t * XDIM + DT_RANK + D_STATE + s];
        const float a  = expf(dt * Aneg);
        h = fmaf(a, h, dt * Bv * u);
        float part = h * Cv;
        part += __shfl_xor(part, 1);
        part += __shfl_xor(part, 2);
        part += __shfl_xor(part, 4);
        part += __shfl_xor(part, 8);
        if (s == 0) {
            const float z = XZ[(size_t)t * (2 * D_INNER) + D_INNER + d];
            YG[(size_t)t * D_INNER + d] = (part + u * Dv) * (z * sigmoidf_(z));
        }
    }
}

extern "C" void kernel_launch(void* const* d_in, const int* in_sizes, int n_in,
                              void* d_out, int out_size, void* d_ws, size_t ws_size,
                              hipStream_t stream)
{
    const float* x        = (const float*)d_in[0];
    const float* norm_w   = (const float*)d_in[1];
    const float* in_proj  = (const float*)d_in[2];
    const float* conv_w   = (const float*)d_in[3];
    const float* conv_b   = (const float*)d_in[4];
    const float* x_proj   = (const float*)d_in[5];
    const float* dt_proj  = (const float*)d_in[6];
    const float* dt_b     = (const float*)d_in[7];
    const float* A_log    = (const float*)d_in[8];
    const float* D_param  = (const float*)d_in[9];
    const float* out_proj = (const float*)d_in[10];

    float* ws = (float*)d_ws;
    float* R     = ws;                     // 2048*384
    float* Xn    = R     + 786432;         // 2048*384
    float* XZ    = Xn    + 786432;         // 2048*1536
    float* XC    = XZ    + 3145728;        // 2048*768
    float* XD    = XC    + 1572864;        // 2048*56
    float* DTb   = XD    + 114688;         // 2048*768
    float* YG    = DTb   + 1572864;        // 2048*768
    float* Aprod = YG    + 1572864;        // 32*768*16
    float* Hpart = Aprod + 393216;         // 32*768*16
    float* Hinit = Hpart + 393216;         // 32*768*16

    hipMemcpyAsync(R, x, (size_t)786432 * sizeof(float), hipMemcpyDeviceToDevice, stream);

    for (int b = 0; b < 6; ++b) {
        rmsnorm_gather_k<<<NTOK, 128, 0, stream>>>(R, norm_w + b * D_MODEL, Xn, b);

        gemm_k<0><<<dim3(2 * D_INNER / 64, NTOK / 64), 256, 0, stream>>>(
            Xn, D_MODEL, in_proj + (size_t)b * 2 * D_INNER * D_MODEL, XZ,
            NTOK, 2 * D_INNER, D_MODEL, nullptr, b);

        conv_silu_k<<<(NTOK * D_INNER) / 256, 256, 0, stream>>>(
            XZ, conv_w + (size_t)b * D_INNER * 4, conv_b + b * D_INNER, XC);

        gemm_k<0><<<dim3(1, NTOK / 64), 256, 0, stream>>>(
            XC, D_INNER, x_proj + (size_t)b * XDIM * D_INNER, XD,
            NTOK, XDIM, D_INNER, nullptr, b);

        gemm_k<1><<<dim3(D_INNER / 64, NTOK / 64), 256, 0, stream>>>(
            XD, XDIM, dt_proj + (size_t)b * D_INNER * DT_RANK, DTb,
            NTOK, D_INNER, DT_RANK, dt_b + b * D_INNER, b);

        scan_phase1_k<<<dim3(D_INNER / 16, NCHUNK), 256, 0, stream>>>(
            XC, DTb, XD, A_log + (size_t)b * D_INNER * D_STATE, Aprod, Hpart);

        scan_phase2_k<<<(D_INNER * D_STATE) / 256, 256, 0, stream>>>(
            Aprod, Hpart, Hinit);

        scan_phase3_k<<<dim3(D_INNER / 16, NCHUNK), 256, 0, stream>>>(
            XC, DTb, XD, XZ, A_log + (size_t)b * D_INNER * D_STATE,
            D_param + b * D_INNER, Hinit, YG);

        gemm_k<2><<<dim3(D_MODEL / 64, NTOK / 64), 256, 0, stream>>>(
            YG, D_INNER, out_proj + (size_t)b * D_MODEL * D_INNER, R,
            NTOK, D_MODEL, D_INNER, nullptr, b);
    }

    hipMemcpyAsync(d_out, R, (size_t)786432 * sizeof(float), hipMemcpyDeviceToDevice, stream);
}

// Round 3
// 1536.009 us; speedup vs baseline: 1.0487x; 1.0487x over previous
//
#include <hip/hip_runtime.h>
#include <math.h>

#define D_MODEL 384
#define D_INNER 768
#define D_STATE 16
#define DT_RANK 24
#define NTOK    2048
#define XDIM    56    // DT_RANK + 2*D_STATE
#define CHUNK   32
#define NCHUNK  (NTOK / CHUNK)   // 64

// ---------- ordering maps: sequence position p -> canonical token (l*256+h*16+w)
__device__ __forceinline__ int tok_of(int order, int p) {
    int q = (order & 1) ? (NTOK - 1 - p) : p;
    int grp = order >> 1;          // 0: HWL, 1: LWH, 2: LHW (canonical)
    int l, h, w;
    if (grp == 0)      { h = q >> 7;  w = (q >> 3) & 15; l = q & 7;  }
    else if (grp == 1) { l = q >> 8;  w = (q >> 4) & 15; h = q & 15; }
    else               { return q; }
    return l * 256 + h * 16 + w;
}

__device__ __forceinline__ float sigmoidf_(float x) { return 1.f / (1.f + expf(-x)); }
__device__ __forceinline__ float softplusf_(float x) { return (x > 20.f) ? x : log1pf(expf(x)); }

// ---------- RMSNorm with gather from canonical residual into sequence order
__global__ __launch_bounds__(128) void rmsnorm_gather_k(
    const float* __restrict__ R, const float* __restrict__ nw,
    float* __restrict__ Xn, int order)
{
    const int p   = blockIdx.x;
    const int tok = tok_of(order, p);
    const float* src = R + tok * D_MODEL;
    const int tid = threadIdx.x;
    float v0 = src[tid], v1 = src[tid + 128], v2 = src[tid + 256];
    float ss = v0 * v0 + v1 * v1 + v2 * v2;
#pragma unroll
    for (int off = 32; off > 0; off >>= 1) ss += __shfl_xor(ss, off);
    __shared__ float tot[2];
    if ((tid & 63) == 0) tot[tid >> 6] = ss;
    __syncthreads();
    const float rs = rsqrtf((tot[0] + tot[1]) * (1.f / D_MODEL) + 1e-5f);
    float* dst = Xn + p * D_MODEL;
    dst[tid]       = v0 * rs * nw[tid];
    dst[tid + 128] = v1 * rs * nw[tid + 128];
    dst[tid + 256] = v2 * rs * nw[tid + 256];
}

// ---------- generic tiled fp32 GEMM: C = A[M,K] * W[N,K]^T
// TRANSA: A passed as [K][M] with leading dim lda (time-major operands).
// MODE 0: plain store C[row*N+col].
// MODE 2: R[tok(row)*N+col] += acc (residual scatter-accumulate).
// MODE 3: transposed store CT[col*NTOK+row].
// MODE 4: transposed store + softplus(acc+bias[col]).
// MODE 5: in_proj split: col<768 -> XP[row*768+col]; col>=768 -> C2[(col-768)*NTOK+row] = silu(acc).
template<int MODE, bool TRANSA>
__global__ __launch_bounds__(256, 2) void gemm_k(
    const float* __restrict__ A, int lda,
    const float* __restrict__ W,
    float* __restrict__ C,
    int M, int N, int K,
    const float* __restrict__ bias,
    float* __restrict__ C2,
    int order)
{
    __shared__ float As[16][68];   // [k][m]
    __shared__ float Ws[16][68];   // [k][n]
    const int tid = threadIdx.x;
    const int m0 = blockIdx.y * 64;
    const int n0 = blockIdx.x * 64;
    const int tx = tid & 15, ty = tid >> 4;
    const int lrow = tid >> 2;          // 0..63
    const int lk   = (tid & 3) << 2;    // 0,4,8,12
    float acc[4][4] = {{0.f}};

    for (int k0 = 0; k0 < K; k0 += 16) {
        if (TRANSA) {
            const int kk = k0 + (tid & 15);
            const int mq = tid >> 4;    // 0..15
            float4 v = make_float4(0.f, 0.f, 0.f, 0.f);
            if (kk < K) v = *(const float4*)&A[kk * lda + m0 + mq * 4];
            *(float4*)&As[tid & 15][mq * 4] = v;
        } else {
            const int m = m0 + lrow;
            const float* src = A + m * lda + (k0 + lk);
            float4 v = make_float4(0.f, 0.f, 0.f, 0.f);
            if (k0 + lk + 3 < K) v = *(const float4*)src;
            else {
                if (k0 + lk + 0 < K) v.x = src[0];
                if (k0 + lk + 1 < K) v.y = src[1];
                if (k0 + lk + 2 < K) v.z = src[2];
            }
            As[lk + 0][lrow] = v.x; As[lk + 1][lrow] = v.y;
            As[lk + 2][lrow] = v.z; As[lk + 3][lrow] = v.w;
        }
        {
            const int n = n0 + lrow;
            float4 u = make_float4(0.f, 0.f, 0.f, 0.f);
            if (n < N) {
                const float* srcw = W + n * K + (k0 + lk);
                if (k0 + lk + 3 < K) u = *(const float4*)srcw;
                else {
                    if (k0 + lk + 0 < K) u.x = srcw[0];
                    if (k0 + lk + 1 < K) u.y = srcw[1];
                    if (k0 + lk + 2 < K) u.z = srcw[2];
                }
            }
            Ws[lk + 0][lrow] = u.x; Ws[lk + 1][lrow] = u.y;
            Ws[lk + 2][lrow] = u.z; Ws[lk + 3][lrow] = u.w;
        }
        __syncthreads();
#pragma unroll
        for (int k = 0; k < 16; ++k) {
            float4 a4 = *(const float4*)&As[k][ty * 4];
            float4 w4 = *(const float4*)&Ws[k][tx * 4];
            float ar[4] = {a4.x, a4.y, a4.z, a4.w};
            float wr[4] = {w4.x, w4.y, w4.z, w4.w};
#pragma unroll
            for (int i = 0; i < 4; ++i)
#pragma unroll
                for (int j = 0; j < 4; ++j)
                    acc[i][j] = fmaf(ar[i], wr[j], acc[i][j]);
        }
        __syncthreads();
    }

    const int row0 = m0 + ty * 4;
    const int col0 = n0 + tx * 4;
    if (MODE == 0) {
#pragma unroll
        for (int i = 0; i < 4; ++i) {
            float4 v = make_float4(acc[i][0], acc[i][1], acc[i][2], acc[i][3]);
            *(float4*)&C[(row0 + i) * N + col0] = v;
        }
    } else if (MODE == 2) {
#pragma unroll
        for (int i = 0; i < 4; ++i) {
            const int tok = tok_of(order, row0 + i);
            float4* dst = (float4*)&C[tok * N + col0];
            float4 r = *dst;
            r.x += acc[i][0]; r.y += acc[i][1]; r.z += acc[i][2]; r.w += acc[i][3];
            *dst = r;
        }
    } else if (MODE == 3) {
#pragma unroll
        for (int j = 0; j < 4; ++j) {
            const int col = col0 + j;
            if (col < N) {
                float4 v = make_float4(acc[0][j], acc[1][j], acc[2][j], acc[3][j]);
                *(float4*)&C[col * NTOK + row0] = v;
            }
        }
    } else if (MODE == 4) {
#pragma unroll
        for (int j = 0; j < 4; ++j) {
            const int col = col0 + j;
            if (col < N) {
                const float bv = bias[col];
                float4 v = make_float4(softplusf_(acc[0][j] + bv), softplusf_(acc[1][j] + bv),
                                       softplusf_(acc[2][j] + bv), softplusf_(acc[3][j] + bv));
                *(float4*)&C[col * NTOK + row0] = v;
            }
        }
    } else if (MODE == 5) {
        if (n0 < D_INNER) {
#pragma unroll
            for (int i = 0; i < 4; ++i) {
                float4 v = make_float4(acc[i][0], acc[i][1], acc[i][2], acc[i][3]);
                *(float4*)&C[(row0 + i) * D_INNER + col0] = v;
            }
        } else {
#pragma unroll
            for (int j = 0; j < 4; ++j) {
                const int c2 = col0 - D_INNER + j;
                float z0 = acc[0][j], z1 = acc[1][j], z2 = acc[2][j], z3 = acc[3][j];
                float4 v = make_float4(z0 * sigmoidf_(z0), z1 * sigmoidf_(z1),
                                       z2 * sigmoidf_(z2), z3 * sigmoidf_(z3));
                *(float4*)&C2[c2 * NTOK + row0] = v;
            }
        }
    }
}

// ---------- causal depthwise conv (k=4) + SiLU; XP[t][d] -> XCT[d][t]
__global__ __launch_bounds__(256) void conv_silu_t_k(
    const float* __restrict__ XP, const float* __restrict__ cw,
    const float* __restrict__ cb, float* __restrict__ XCT)
{
    __shared__ float xs[67][33];
    const int c0 = blockIdx.x * 32;
    const int t0 = blockIdx.y * 64;
    const int tid = threadIdx.x;
    const int col = tid & 31, rr = tid >> 5;
#pragma unroll
    for (int r = rr; r < 67; r += 8) {
        const int t = t0 - 3 + r;
        xs[r][col] = (t >= 0) ? XP[t * D_INNER + c0 + col] : 0.f;
    }
    __syncthreads();
    const int tl = tid & 63;
#pragma unroll
    for (int cl = tid >> 6; cl < 32; cl += 4) {
        const int c = c0 + cl;
        const float4 w4 = *(const float4*)(cw + c * 4);
        float acc = cb[c];
        acc = fmaf(w4.x, xs[tl + 0][cl], acc);
        acc = fmaf(w4.y, xs[tl + 1][cl], acc);
        acc = fmaf(w4.z, xs[tl + 2][cl], acc);
        acc = fmaf(w4.w, xs[tl + 3][cl], acc);
        XCT[c * NTOK + t0 + tl] = acc * sigmoidf_(acc);
    }
}

// ---------- chunked selective scan, phase 1: per-chunk (prod a, partial h) from h=0
__global__ __launch_bounds__(256) void scan_phase1_k(
    const float* __restrict__ XCT, const float* __restrict__ DTT,
    const float* __restrict__ XDT, const float* __restrict__ A_log,
    float* __restrict__ Aprod, float* __restrict__ Hpart)
{
    const int tid = threadIdx.x;
    const int s = tid & 15;
    const int d = blockIdx.x * 16 + (tid >> 4);
    const int chunk = blockIdx.y;
    const float Aneg = -expf(A_log[d * D_STATE + s]);
    const float* dtp = DTT + d * NTOK + chunk * CHUNK;
    const float* up  = XCT + d * NTOK + chunk * CHUNK;
    const float* Bp  = XDT + (DT_RANK + s) * NTOK + chunk * CHUNK;
    float h = 0.f, ap = 1.f;
#pragma unroll
    for (int tt = 0; tt < CHUNK; tt += 4) {
        const float4 dt4 = *(const float4*)(dtp + tt);
        const float4 u4  = *(const float4*)(up + tt);
        const float4 B4  = *(const float4*)(Bp + tt);
        float a;
        a = expf(dt4.x * Aneg); h = fmaf(a, h, dt4.x * B4.x * u4.x); ap *= a;
        a = expf(dt4.y * Aneg); h = fmaf(a, h, dt4.y * B4.y * u4.y); ap *= a;
        a = expf(dt4.z * Aneg); h = fmaf(a, h, dt4.z * B4.z * u4.z); ap *= a;
        a = expf(dt4.w * Aneg); h = fmaf(a, h, dt4.w * B4.w * u4.w); ap *= a;
    }
    const int idx = (chunk * D_INNER + d) * D_STATE + s;
    Aprod[idx] = ap;
    Hpart[idx] = h;
}

// ---------- phase 2: sequential scan over chunk summaries -> per-chunk initial h
__global__ __launch_bounds__(256) void scan_phase2_k(
    const float* __restrict__ Aprod, const float* __restrict__ Hpart,
    float* __restrict__ Hinit)
{
    const int tid = blockIdx.x * 256 + threadIdx.x;   // d*16+s, 12288 total
    float h = 0.f;
#pragma unroll 8
    for (int c = 0; c < NCHUNK; ++c) {
        const int idx = c * (D_INNER * D_STATE) + tid;
        Hinit[idx] = h;
        h = fmaf(Aprod[idx], h, Hpart[idx]);
    }
}

// ---------- phase 3: recompute within chunk from correct h0; fused u*D + gate
__global__ __launch_bounds__(256) void scan_phase3_k(
    const float* __restrict__ XCT, const float* __restrict__ DTT,
    const float* __restrict__ XDT, const float* __restrict__ GT,
    const float* __restrict__ A_log, const float* __restrict__ Dp,
    const float* __restrict__ Hinit, float* __restrict__ YGT)
{
    const int tid = threadIdx.x;
    const int s = tid & 15;
    const int d = blockIdx.x * 16 + (tid >> 4);
    const int chunk = blockIdx.y;
    const float Aneg = -expf(A_log[d * D_STATE + s]);
    const float Dv = Dp[d];
    const float* dtp = DTT + d * NTOK + chunk * CHUNK;
    const float* up  = XCT + d * NTOK + chunk * CHUNK;
    const float* Bp  = XDT + (DT_RANK + s) * NTOK + chunk * CHUNK;
    const float* Cp  = XDT + (DT_RANK + D_STATE + s) * NTOK + chunk * CHUNK;
    const float* Gp  = GT  + d * NTOK + chunk * CHUNK;
    float* Yp        = YGT + d * NTOK + chunk * CHUNK;
    float h = Hinit[(chunk * D_INNER + d) * D_STATE + s];
#pragma unroll
    for (int tt = 0; tt < CHUNK; tt += 4) {
        const float4 dt4 = *(const float4*)(dtp + tt);
        const float4 u4  = *(const float4*)(up + tt);
        const float4 B4  = *(const float4*)(Bp + tt);
        const float4 C4  = *(const float4*)(Cp + tt);
        float a, p0, p1, p2, p3;
        a = expf(dt4.x * Aneg); h = fmaf(a, h, dt4.x * B4.x * u4.x); p0 = h * C4.x;
        a = expf(dt4.y * Aneg); h = fmaf(a, h, dt4.y * B4.y * u4.y); p1 = h * C4.y;
        a = expf(dt4.z * Aneg); h = fmaf(a, h, dt4.z * B4.z * u4.z); p2 = h * C4.z;
        a = expf(dt4.w * Aneg); h = fmaf(a, h, dt4.w * B4.w * u4.w); p3 = h * C4.w;
#pragma unroll
        for (int m = 1; m <= 8; m <<= 1) {
            p0 += __shfl_xor(p0, m); p1 += __shfl_xor(p1, m);
            p2 += __shfl_xor(p2, m); p3 += __shfl_xor(p3, m);
        }
        if (s == 0) {
            const float4 g4 = *(const float4*)(Gp + tt);
            float4 y;
            y.x = (p0 + u4.x * Dv) * g4.x;
            y.y = (p1 + u4.y * Dv) * g4.y;
            y.z = (p2 + u4.z * Dv) * g4.z;
            y.w = (p3 + u4.w * Dv) * g4.w;
            *(float4*)(Yp + tt) = y;
        }
    }
}

extern "C" void kernel_launch(void* const* d_in, const int* in_sizes, int n_in,
                              void* d_out, int out_size, void* d_ws, size_t ws_size,
                              hipStream_t stream)
{
    const float* x        = (const float*)d_in[0];
    const float* norm_w   = (const float*)d_in[1];
    const float* in_proj  = (const float*)d_in[2];
    const float* conv_w   = (const float*)d_in[3];
    const float* conv_b   = (const float*)d_in[4];
    const float* x_proj   = (const float*)d_in[5];
    const float* dt_proj  = (const float*)d_in[6];
    const float* dt_b     = (const float*)d_in[7];
    const float* A_log    = (const float*)d_in[8];
    const float* D_param  = (const float*)d_in[9];
    const float* out_proj = (const float*)d_in[10];

    float* ws = (float*)d_ws;
    float* R     = ws;                     // 786432
    float* XP    = R   + 786432;           // 1572864   (Hinit aliases, written after XP dead)
    float* Xn    = XP  + 1572864;          // 786432    (Aprod aliases, written after Xn dead)
    float* GT    = Xn  + 786432;           // 1572864
    float* XCT   = GT  + 1572864;          // 1572864
    float* XDT   = XCT + 1572864;          // 114688
    float* DTT   = XDT + 114688;           // 1572864
    float* YGT   = DTT + 1572864;          // 1572864   (Hpart aliases, clobbered by phase3 after use)
    float* Aprod = Xn;
    float* Hpart = YGT;
    float* Hinit = XP;

    hipMemcpyAsync(R, x, (size_t)786432 * sizeof(float), hipMemcpyDeviceToDevice, stream);

    for (int b = 0; b < 6; ++b) {
        rmsnorm_gather_k<<<NTOK, 128, 0, stream>>>(R, norm_w + b * D_MODEL, Xn, b);

        // in_proj: Xn(2048x384) x W(1536x384)^T -> XP[t][d] (xp half), GT[d][t]=silu(z half)
        gemm_k<5, false><<<dim3(24, 32), 256, 0, stream>>>(
            Xn, D_MODEL, in_proj + (size_t)b * 2 * D_INNER * D_MODEL, XP,
            NTOK, 2 * D_INNER, D_MODEL, nullptr, GT, b);

        conv_silu_t_k<<<dim3(24, 32), 256, 0, stream>>>(
            XP, conv_w + b * D_INNER * 4, conv_b + b * D_INNER, XCT);

        // x_proj: (XCT^T)(2048x768) x W(56x768)^T -> XDT[e][t]
        gemm_k<3, true><<<dim3(1, 32), 256, 0, stream>>>(
            XCT, NTOK, x_proj + (size_t)b * XDIM * D_INNER, XDT,
            NTOK, XDIM, D_INNER, nullptr, nullptr, b);

        // dt_proj: (XDT rows 0..23)^T (2048x24) x W(768x24)^T -> DTT[d][t] softplus+bias
        gemm_k<4, true><<<dim3(12, 32), 256, 0, stream>>>(
            XDT, NTOK, dt_proj + (size_t)b * D_INNER * DT_RANK, DTT,
            NTOK, D_INNER, DT_RANK, dt_b + b * D_INNER, nullptr, b);

        scan_phase1_k<<<dim3(48, NCHUNK), 256, 0, stream>>>(
            XCT, DTT, XDT, A_log + (size_t)b * D_INNER * D_STATE, Aprod, Hpart);

        scan_phase2_k<<<48, 256, 0, stream>>>(Aprod, Hpart, Hinit);

        scan_phase3_k<<<dim3(48, NCHUNK), 256, 0, stream>>>(
            XCT, DTT, XDT, GT, A_log + (size_t)b * D_INNER * D_STATE,
            D_param + b * D_INNER, Hinit, YGT);

        // out_proj: (YGT^T)(2048x768) x W(384x768)^T -> scatter-accumulate into R
        gemm_k<2, true><<<dim3(6, 32), 256, 0, stream>>>(
            YGT, NTOK, out_proj + (size_t)b * D_MODEL * D_INNER, R,
            NTOK, D_MODEL, D_INNER, nullptr, nullptr, b);
    }

    hipMemcpyAsync(d_out, R, (size_t)786432 * sizeof(float), hipMemcpyDeviceToDevice, stream);
}

// Round 5
// 1069.984 us; speedup vs baseline: 1.5055x; 1.4355x over previous
//
#include <hip/hip_runtime.h>
#include <math.h>

#define D_MODEL 384
#define D_INNER 768
#define D_STATE 16
#define DT_RANK 24
#define NTOK    2048
#define XDIM    56    // DT_RANK + 2*D_STATE
#define CHUNK   32
#define NCHUNK  (NTOK / CHUNK)   // 64

// ---------- ordering maps: sequence position p -> canonical token (l*256+h*16+w)
__device__ __forceinline__ int tok_of(int order, int p) {
    int q = (order & 1) ? (NTOK - 1 - p) : p;
    int grp = order >> 1;          // 0: HWL, 1: LWH, 2: LHW (canonical)
    int l, h, w;
    if (grp == 0)      { h = q >> 7;  w = (q >> 3) & 15; l = q & 7;  }
    else if (grp == 1) { l = q >> 8;  w = (q >> 4) & 15; h = q & 15; }
    else               { return q; }
    return l * 256 + h * 16 + w;
}

__device__ __forceinline__ float sigmoidf_(float x) { return 1.f / (1.f + expf(-x)); }
__device__ __forceinline__ float softplusf_(float x) { return (x > 20.f) ? x : log1pf(expf(x)); }

// ---------- RMSNorm with gather from canonical residual into sequence order
__global__ __launch_bounds__(128) void rmsnorm_gather_k(
    const float* __restrict__ R, const float* __restrict__ nw,
    float* __restrict__ Xn, int order)
{
    const int p   = blockIdx.x;
    const int tok = tok_of(order, p);
    const float* src = R + tok * D_MODEL;
    const int tid = threadIdx.x;
    float v0 = src[tid], v1 = src[tid + 128], v2 = src[tid + 256];
    float ss = v0 * v0 + v1 * v1 + v2 * v2;
#pragma unroll
    for (int off = 32; off > 0; off >>= 1) ss += __shfl_xor(ss, off);
    __shared__ float tot[2];
    if ((tid & 63) == 0) tot[tid >> 6] = ss;
    __syncthreads();
    const float rs = rsqrtf((tot[0] + tot[1]) * (1.f / D_MODEL) + 1e-5f);
    float* dst = Xn + p * D_MODEL;
    dst[tid]       = v0 * rs * nw[tid];
    dst[tid + 128] = v1 * rs * nw[tid + 128];
    dst[tid + 256] = v2 * rs * nw[tid + 256];
}

// ---------- generic tiled fp32 GEMM: C = A[M,K] * W[N,K]^T   (split-K via blockIdx.z)
// TRANSA: A passed as [K][M] with leading dim lda (time-major operands).
// kspan: K-range per z-slice (multiple of 16 except trailing masked tail).
// MODE 0: plain store C[z*M*N + row*N+col].
// MODE 3: transposed store C[z*N*NTOK + col*NTOK+row].
// MODE 4: transposed store + softplus(acc+bias[col]).
// MODE 5: in_proj split: col<768 -> XP[row*768+col]; col>=768 -> C2[(col-768)*NTOK+row] = silu(acc).
template<int MODE, bool TRANSA>
__global__ __launch_bounds__(256, 2) void gemm_k(
    const float* __restrict__ A, int lda,
    const float* __restrict__ W,
    float* __restrict__ C,
    int M, int N, int K,
    const float* __restrict__ bias,
    float* __restrict__ C2,
    int kspan)
{
    __shared__ float As[16][68];   // [k][m]
    __shared__ float Ws[16][68];   // [k][n]
    const int tid = threadIdx.x;
    const int m0 = blockIdx.y * 64;
    const int n0 = blockIdx.x * 64;
    const int tx = tid & 15, ty = tid >> 4;
    const int lrow = tid >> 2;          // 0..63
    const int lk   = (tid & 3) << 2;    // 0,4,8,12
    const int kb   = blockIdx.z * kspan;
    const int ke   = (kb + kspan < K) ? (kb + kspan) : K;
    float acc[4][4] = {{0.f}};

    for (int k0 = kb; k0 < ke; k0 += 16) {
        if (TRANSA) {
            const int kk = k0 + (tid & 15);
            const int mq = tid >> 4;    // 0..15
            float4 v = make_float4(0.f, 0.f, 0.f, 0.f);
            if (kk < K) v = *(const float4*)&A[kk * lda + m0 + mq * 4];
            *(float4*)&As[tid & 15][mq * 4] = v;
        } else {
            const int m = m0 + lrow;
            const float* src = A + m * lda + (k0 + lk);
            float4 v = make_float4(0.f, 0.f, 0.f, 0.f);
            if (k0 + lk + 3 < K) v = *(const float4*)src;
            else {
                if (k0 + lk + 0 < K) v.x = src[0];
                if (k0 + lk + 1 < K) v.y = src[1];
                if (k0 + lk + 2 < K) v.z = src[2];
            }
            As[lk + 0][lrow] = v.x; As[lk + 1][lrow] = v.y;
            As[lk + 2][lrow] = v.z; As[lk + 3][lrow] = v.w;
        }
        {
            const int n = n0 + lrow;
            float4 u = make_float4(0.f, 0.f, 0.f, 0.f);
            if (n < N) {
                const float* srcw = W + n * K + (k0 + lk);
                if (k0 + lk + 3 < K) u = *(const float4*)srcw;
                else {
                    if (k0 + lk + 0 < K) u.x = srcw[0];
                    if (k0 + lk + 1 < K) u.y = srcw[1];
                    if (k0 + lk + 2 < K) u.z = srcw[2];
                }
            }
            Ws[lk + 0][lrow] = u.x; Ws[lk + 1][lrow] = u.y;
            Ws[lk + 2][lrow] = u.z; Ws[lk + 3][lrow] = u.w;
        }
        __syncthreads();
#pragma unroll
        for (int k = 0; k < 16; ++k) {
            float4 a4 = *(const float4*)&As[k][ty * 4];
            float4 w4 = *(const float4*)&Ws[k][tx * 4];
            float ar[4] = {a4.x, a4.y, a4.z, a4.w};
            float wr[4] = {w4.x, w4.y, w4.z, w4.w};
#pragma unroll
            for (int i = 0; i < 4; ++i)
#pragma unroll
                for (int j = 0; j < 4; ++j)
                    acc[i][j] = fmaf(ar[i], wr[j], acc[i][j]);
        }
        __syncthreads();
    }

    const int row0 = m0 + ty * 4;
    const int col0 = n0 + tx * 4;
    if (MODE == 0) {
        float* Cz = C + (size_t)blockIdx.z * M * N;
#pragma unroll
        for (int i = 0; i < 4; ++i) {
            float4 v = make_float4(acc[i][0], acc[i][1], acc[i][2], acc[i][3]);
            *(float4*)&Cz[(row0 + i) * N + col0] = v;
        }
    } else if (MODE == 3) {
        float* Cz = C + (size_t)blockIdx.z * N * NTOK;
#pragma unroll
        for (int j = 0; j < 4; ++j) {
            const int col = col0 + j;
            if (col < N) {
                float4 v = make_float4(acc[0][j], acc[1][j], acc[2][j], acc[3][j]);
                *(float4*)&Cz[col * NTOK + row0] = v;
            }
        }
    } else if (MODE == 4) {
#pragma unroll
        for (int j = 0; j < 4; ++j) {
            const int col = col0 + j;
            if (col < N) {
                const float bv = bias[col];
                float4 v = make_float4(softplusf_(acc[0][j] + bv), softplusf_(acc[1][j] + bv),
                                       softplusf_(acc[2][j] + bv), softplusf_(acc[3][j] + bv));
                *(float4*)&C[col * NTOK + row0] = v;
            }
        }
    } else if (MODE == 5) {
        if (n0 < D_INNER) {
#pragma unroll
            for (int i = 0; i < 4; ++i) {
                float4 v = make_float4(acc[i][0], acc[i][1], acc[i][2], acc[i][3]);
                *(float4*)&C[(row0 + i) * D_INNER + col0] = v;
            }
        } else {
#pragma unroll
            for (int j = 0; j < 4; ++j) {
                const int c2 = col0 - D_INNER + j;
                float z0 = acc[0][j], z1 = acc[1][j], z2 = acc[2][j], z3 = acc[3][j];
                float4 v = make_float4(z0 * sigmoidf_(z0), z1 * sigmoidf_(z1),
                                       z2 * sigmoidf_(z2), z3 * sigmoidf_(z3));
                *(float4*)&C2[c2 * NTOK + row0] = v;
            }
        }
    }
}

// ---------- reduce split-K partials PX[8][56][2048] -> XDT[e][t]  (float4)
__global__ __launch_bounds__(256) void reduce_px_k(
    const float* __restrict__ PX, float* __restrict__ XDT)
{
    const int i4 = blockIdx.x * 256 + threadIdx.x;        // 28672 float4 elems
    float4 s = ((const float4*)PX)[i4];
#pragma unroll
    for (int z = 1; z < 8; ++z) {
        float4 v = ((const float4*)PX)[z * (XDIM * NTOK / 4) + i4];
        s.x += v.x; s.y += v.y; s.z += v.z; s.w += v.w;
    }
    ((float4*)XDT)[i4] = s;
}

// ---------- reduce split-K partials PO[4][2048][384] + scatter-accumulate into R
__global__ __launch_bounds__(384) void reduce_scatter_k(
    const float* __restrict__ PO, float* __restrict__ R, int order)
{
    const int m = blockIdx.x;
    const int col = threadIdx.x;
    float s = PO[m * D_MODEL + col];
#pragma unroll
    for (int z = 1; z < 4; ++z)
        s += PO[z * (NTOK * D_MODEL) + m * D_MODEL + col];
    const int tok = tok_of(order, m);
    R[tok * D_MODEL + col] += s;
}

// ---------- causal depthwise conv (k=4) + SiLU; XP[t][d] -> XCT[d][t]
__global__ __launch_bounds__(256) void conv_silu_t_k(
    const float* __restrict__ XP, const float* __restrict__ cw,
    const float* __restrict__ cb, float* __restrict__ XCT)
{
    __shared__ float xs[67][33];
    const int c0 = blockIdx.x * 32;
    const int t0 = blockIdx.y * 64;
    const int tid = threadIdx.x;
    const int col = tid & 31, rr = tid >> 5;
#pragma unroll
    for (int r = rr; r < 67; r += 8) {
        const int t = t0 - 3 + r;
        xs[r][col] = (t >= 0) ? XP[t * D_INNER + c0 + col] : 0.f;
    }
    __syncthreads();
    const int tl = tid & 63;
#pragma unroll
    for (int cl = tid >> 6; cl < 32; cl += 4) {
        const int c = c0 + cl;
        const float4 w4 = *(const float4*)(cw + c * 4);
        float acc = cb[c];
        acc = fmaf(w4.x, xs[tl + 0][cl], acc);
        acc = fmaf(w4.y, xs[tl + 1][cl], acc);
        acc = fmaf(w4.z, xs[tl + 2][cl], acc);
        acc = fmaf(w4.w, xs[tl + 3][cl], acc);
        XCT[c * NTOK + t0 + tl] = acc * sigmoidf_(acc);
    }
}

// ---------- chunked selective scan, phase 1: per-chunk (prod a, partial h) from h=0
__global__ __launch_bounds__(256) void scan_phase1_k(
    const float* __restrict__ XCT, const float* __restrict__ DTT,
    const float* __restrict__ XDT, const float* __restrict__ A_log,
    float* __restrict__ Aprod, float* __restrict__ Hpart)
{
    const int tid = threadIdx.x;
    const int s = tid & 15;
    const int d = blockIdx.x * 16 + (tid >> 4);
    const int chunk = blockIdx.y;
    const float Aneg = -expf(A_log[d * D_STATE + s]);
    const float* dtp = DTT + d * NTOK + chunk * CHUNK;
    const float* up  = XCT + d * NTOK + chunk * CHUNK;
    const float* Bp  = XDT + (DT_RANK + s) * NTOK + chunk * CHUNK;
    float h = 0.f, ap = 1.f;
#pragma unroll
    for (int tt = 0; tt < CHUNK; tt += 4) {
        const float4 dt4 = *(const float4*)(dtp + tt);
        const float4 u4  = *(const float4*)(up + tt);
        const float4 B4  = *(const float4*)(Bp + tt);
        float a;
        a = expf(dt4.x * Aneg); h = fmaf(a, h, dt4.x * B4.x * u4.x); ap *= a;
        a = expf(dt4.y * Aneg); h = fmaf(a, h, dt4.y * B4.y * u4.y); ap *= a;
        a = expf(dt4.z * Aneg); h = fmaf(a, h, dt4.z * B4.z * u4.z); ap *= a;
        a = expf(dt4.w * Aneg); h = fmaf(a, h, dt4.w * B4.w * u4.w); ap *= a;
    }
    const int idx = (chunk * D_INNER + d) * D_STATE + s;
    Aprod[idx] = ap;
    Hpart[idx] = h;
}

// ---------- phase 2: sequential scan over chunk summaries -> per-chunk initial h
__global__ __launch_bounds__(256) void scan_phase2_k(
    const float* __restrict__ Aprod, const float* __restrict__ Hpart,
    float* __restrict__ Hinit)
{
    const int tid = blockIdx.x * 256 + threadIdx.x;   // d*16+s, 12288 total
    float h = 0.f;
#pragma unroll 8
    for (int c = 0; c < NCHUNK; ++c) {
        const int idx = c * (D_INNER * D_STATE) + tid;
        Hinit[idx] = h;
        h = fmaf(Aprod[idx], h, Hpart[idx]);
    }
}

// ---------- phase 3: recompute within chunk from correct h0; fused u*D + gate
__global__ __launch_bounds__(256) void scan_phase3_k(
    const float* __restrict__ XCT, const float* __restrict__ DTT,
    const float* __restrict__ XDT, const float* __restrict__ GT,
    const float* __restrict__ A_log, const float* __restrict__ Dp,
    const float* __restrict__ Hinit, float* __restrict__ YGT)
{
    const int tid = threadIdx.x;
    const int s = tid & 15;
    const int d = blockIdx.x * 16 + (tid >> 4);
    const int chunk = blockIdx.y;
    const float Aneg = -expf(A_log[d * D_STATE + s]);
    const float Dv = Dp[d];
    const float* dtp = DTT + d * NTOK + chunk * CHUNK;
    const float* up  = XCT + d * NTOK + chunk * CHUNK;
    const float* Bp  = XDT + (DT_RANK + s) * NTOK + chunk * CHUNK;
    const float* Cp  = XDT + (DT_RANK + D_STATE + s) * NTOK + chunk * CHUNK;
    const float* Gp  = GT  + d * NTOK + chunk * CHUNK;
    float* Yp        = YGT + d * NTOK + chunk * CHUNK;
    float h = Hinit[(chunk * D_INNER + d) * D_STATE + s];
#pragma unroll
    for (int tt = 0; tt < CHUNK; tt += 4) {
        const float4 dt4 = *(const float4*)(dtp + tt);
        const float4 u4  = *(const float4*)(up + tt);
        const float4 B4  = *(const float4*)(Bp + tt);
        const float4 C4  = *(const float4*)(Cp + tt);
        float a, p0, p1, p2, p3;
        a = expf(dt4.x * Aneg); h = fmaf(a, h, dt4.x * B4.x * u4.x); p0 = h * C4.x;
        a = expf(dt4.y * Aneg); h = fmaf(a, h, dt4.y * B4.y * u4.y); p1 = h * C4.y;
        a = expf(dt4.z * Aneg); h = fmaf(a, h, dt4.z * B4.z * u4.z); p2 = h * C4.z;
        a = expf(dt4.w * Aneg); h = fmaf(a, h, dt4.w * B4.w * u4.w); p3 = h * C4.w;
#pragma unroll
        for (int m = 1; m <= 8; m <<= 1) {
            p0 += __shfl_xor(p0, m); p1 += __shfl_xor(p1, m);
            p2 += __shfl_xor(p2, m); p3 += __shfl_xor(p3, m);
        }
        if (s == 0) {
            const float4 g4 = *(const float4*)(Gp + tt);
            float4 y;
            y.x = (p0 + u4.x * Dv) * g4.x;
            y.y = (p1 + u4.y * Dv) * g4.y;
            y.z = (p2 + u4.z * Dv) * g4.z;
            y.w = (p3 + u4.w * Dv) * g4.w;
            *(float4*)(Yp + tt) = y;
        }
    }
}

extern "C" void kernel_launch(void* const* d_in, const int* in_sizes, int n_in,
                              void* d_out, int out_size, void* d_ws, size_t ws_size,
                              hipStream_t stream)
{
    const float* x        = (const float*)d_in[0];
    const float* norm_w   = (const float*)d_in[1];
    const float* in_proj  = (const float*)d_in[2];
    const float* conv_w   = (const float*)d_in[3];
    const float* conv_b   = (const float*)d_in[4];
    const float* x_proj   = (const float*)d_in[5];
    const float* dt_proj  = (const float*)d_in[6];
    const float* dt_b     = (const float*)d_in[7];
    const float* A_log    = (const float*)d_in[8];
    const float* D_param  = (const float*)d_in[9];
    const float* out_proj = (const float*)d_in[10];

    float* ws = (float*)d_ws;
    float* R     = ws;                     // 786432
    float* XP    = R   + 786432;           // 1572864 (aliases: PX first 917504; Hinit 786432 later)
    float* Xn    = XP  + 1572864;          // 786432  (alias: Aprod)
    float* GT    = Xn  + 786432;           // 1572864 ┐ PO = GT..XCT (3145728) after phase3
    float* XCT   = GT  + 1572864;          // 1572864 ┘
    float* XDT   = XCT + 1572864;          // 114688
    float* DTT   = XDT + 114688;           // 1572864
    float* YGT   = DTT + 1572864;          // 1572864 (alias: Hpart)
    float* Aprod = Xn;
    float* Hpart = YGT;
    float* Hinit = XP;
    float* PX    = XP;      // 8*56*2048 = 917504, live only conv-done -> reduce_px
    float* PO    = GT;      // 4*2048*384 = 3145728, live only after phase3

    hipMemcpyAsync(R, x, (size_t)786432 * sizeof(float), hipMemcpyDeviceToDevice, stream);

    for (int b = 0; b < 6; ++b) {
        rmsnorm_gather_k<<<NTOK, 128, 0, stream>>>(R, norm_w + b * D_MODEL, Xn, b);

        // in_proj: Xn(2048x384) x W(1536x384)^T -> XP[t][d] (xp half), GT[d][t]=silu(z half)
        gemm_k<5, false><<<dim3(24, 32, 1), 256, 0, stream>>>(
            Xn, D_MODEL, in_proj + (size_t)b * 2 * D_INNER * D_MODEL, XP,
            NTOK, 2 * D_INNER, D_MODEL, nullptr, GT, D_MODEL);

        conv_silu_t_k<<<dim3(24, 32), 256, 0, stream>>>(
            XP, conv_w + b * D_INNER * 4, conv_b + b * D_INNER, XCT);

        // x_proj split-K: (XCT^T)(2048x768) x W(56x768)^T -> PX[z][e][t], K=96/slice
        gemm_k<3, true><<<dim3(1, 32, 8), 256, 0, stream>>>(
            XCT, NTOK, x_proj + (size_t)b * XDIM * D_INNER, PX,
            NTOK, XDIM, D_INNER, nullptr, nullptr, 96);

        reduce_px_k<<<112, 256, 0, stream>>>(PX, XDT);

        // dt_proj: (XDT rows 0..23)^T (2048x24) x W(768x24)^T -> DTT[d][t] softplus+bias
        gemm_k<4, true><<<dim3(12, 32, 1), 256, 0, stream>>>(
            XDT, NTOK, dt_proj + (size_t)b * D_INNER * DT_RANK, DTT,
            NTOK, D_INNER, DT_RANK, dt_b + b * D_INNER, nullptr, DT_RANK);

        scan_phase1_k<<<dim3(48, NCHUNK), 256, 0, stream>>>(
            XCT, DTT, XDT, A_log + (size_t)b * D_INNER * D_STATE, Aprod, Hpart);

        scan_phase2_k<<<48, 256, 0, stream>>>(Aprod, Hpart, Hinit);

        scan_phase3_k<<<dim3(48, NCHUNK), 256, 0, stream>>>(
            XCT, DTT, XDT, GT, A_log + (size_t)b * D_INNER * D_STATE,
            D_param + b * D_INNER, Hinit, YGT);

        // out_proj split-K: (YGT^T)(2048x768) x W(384x768)^T -> PO[z][t][d], K=192/slice
        gemm_k<0, true><<<dim3(6, 32, 4), 256, 0, stream>>>(
            YGT, NTOK, out_proj + (size_t)b * D_MODEL * D_INNER, PO,
            NTOK, D_MODEL, D_INNER, nullptr, nullptr, 192);

        reduce_scatter_k<<<NTOK, 384, 0, stream>>>(PO, R, b);
    }

    hipMemcpyAsync(d_out, R, (size_t)786432 * sizeof(float), hipMemcpyDeviceToDevice, stream);
}

// Round 6
// 937.073 us; speedup vs baseline: 1.7191x; 1.1418x over previous
//
#include <hip/hip_runtime.h>
#include <math.h>

#define D_MODEL 384
#define D_INNER 768
#define D_STATE 16
#define DT_RANK 24
#define NTOK    2048
#define XDIM    56    // DT_RANK + 2*D_STATE
#define CHUNK   32
#define NCHUNK  (NTOK / CHUNK)   // 64

typedef __attribute__((ext_vector_type(8))) short bf16x8;
typedef __attribute__((ext_vector_type(4))) float f32x4;

// ---------- ordering maps: sequence position p -> canonical token (l*256+h*16+w)
__device__ __forceinline__ int tok_of(int order, int p) {
    int q = (order & 1) ? (NTOK - 1 - p) : p;
    int grp = order >> 1;          // 0: HWL, 1: LWH, 2: LHW (canonical)
    int l, h, w;
    if (grp == 0)      { h = q >> 7;  w = (q >> 3) & 15; l = q & 7;  }
    else if (grp == 1) { l = q >> 8;  w = (q >> 4) & 15; h = q & 15; }
    else               { return q; }
    return l * 256 + h * 16 + w;
}

__device__ __forceinline__ float sigmoidf_(float x) { return 1.f / (1.f + expf(-x)); }
__device__ __forceinline__ float softplusf_(float x) { return (x > 20.f) ? x : log1pf(expf(x)); }

// split fp32 -> bf16 hi (truncate) + bf16 lo (residual, truncate)
__device__ __forceinline__ void bf16split_(float a, unsigned short& hb, unsigned short& lb) {
    unsigned int ab = __float_as_uint(a);
    hb = (unsigned short)(ab >> 16);
    float hf = __uint_as_float(ab & 0xFFFF0000u);
    lb = (unsigned short)(__float_as_uint(a - hf) >> 16);
}

// ---------- RMSNorm with gather from canonical residual into sequence order
__global__ __launch_bounds__(128) void rmsnorm_gather_k(
    const float* __restrict__ R, const float* __restrict__ nw,
    float* __restrict__ Xn, int order)
{
    const int p   = blockIdx.x;
    const int tok = tok_of(order, p);
    const float* src = R + tok * D_MODEL;
    const int tid = threadIdx.x;
    float v0 = src[tid], v1 = src[tid + 128], v2 = src[tid + 256];
    float ss = v0 * v0 + v1 * v1 + v2 * v2;
#pragma unroll
    for (int off = 32; off > 0; off >>= 1) ss += __shfl_xor(ss, off);
    __shared__ float tot[2];
    if ((tid & 63) == 0) tot[tid >> 6] = ss;
    __syncthreads();
    const float rs = rsqrtf((tot[0] + tot[1]) * (1.f / D_MODEL) + 1e-5f);
    float* dst = Xn + p * D_MODEL;
    dst[tid]       = v0 * rs * nw[tid];
    dst[tid + 128] = v1 * rs * nw[tid + 128];
    dst[tid + 256] = v2 * rs * nw[tid + 256];
}

// ---------- in_proj via bf16x3 MFMA: C[2048x1536] = Xn[2048x384] * W[1536x384]^T
// n<768  -> XP[t*768+n] = c
// n>=768 -> GT[(n-768)*2048+t] = silu(c)
__global__ __launch_bounds__(256, 3) void inproj_mfma_k(
    const float* __restrict__ Xn, const float* __restrict__ W,
    float* __restrict__ XP, float* __restrict__ GT)
{
    // [kgrp][row][8] bf16 chunks; every fragment read is one aligned ds_read_b128
    __shared__ __align__(16) short Ah[4 * 64 * 8];
    __shared__ __align__(16) short Al[4 * 64 * 8];
    __shared__ __align__(16) short Bh[4 * 64 * 8];
    __shared__ __align__(16) short Bl[4 * 64 * 8];

    const int tid = threadIdx.x;
    const int m0 = blockIdx.y * 64;
    const int n0 = blockIdx.x * 64;
    const int w  = tid >> 6;        // wave 0..3 -> 16-col strip
    const int l  = tid & 63;
    const int lr = l & 15;          // fragment row/col
    const int kg = l >> 4;          // k-group 0..3
    const int srow = tid >> 2;      // staging row 0..63
    const int skq  = tid & 3;       // staging k-quarter 0..3

    f32x4 acc[4];
#pragma unroll
    for (int r = 0; r < 4; ++r) acc[r] = (f32x4){0.f, 0.f, 0.f, 0.f};

    for (int k0 = 0; k0 < D_MODEL; k0 += 32) {
        // ---- stage A (Xn) and B (W) tiles, split hi/lo
        {
            const float* ap = Xn + (m0 + srow) * D_MODEL + k0 + skq * 8;
            const float4 a0 = *(const float4*)ap;
            const float4 a1 = *(const float4*)(ap + 4);
            const float av[8] = {a0.x, a0.y, a0.z, a0.w, a1.x, a1.y, a1.z, a1.w};
            union { bf16x8 v; unsigned short u[8]; } hu, lu;
#pragma unroll
            for (int j = 0; j < 8; ++j) bf16split_(av[j], hu.u[j], lu.u[j]);
            *(bf16x8*)&Ah[(skq * 64 + srow) * 8] = hu.v;
            *(bf16x8*)&Al[(skq * 64 + srow) * 8] = lu.v;

            const float* wp = W + (n0 + srow) * D_MODEL + k0 + skq * 8;
            const float4 w0 = *(const float4*)wp;
            const float4 w1 = *(const float4*)(wp + 4);
            const float wv[8] = {w0.x, w0.y, w0.z, w0.w, w1.x, w1.y, w1.z, w1.w};
            union { bf16x8 v; unsigned short u[8]; } hw, lw;
#pragma unroll
            for (int j = 0; j < 8; ++j) bf16split_(wv[j], hw.u[j], lw.u[j]);
            *(bf16x8*)&Bh[(skq * 64 + srow) * 8] = hw.v;
            *(bf16x8*)&Bl[(skq * 64 + srow) * 8] = lw.v;
        }
        __syncthreads();

        const bf16x8 bh = *(const bf16x8*)&Bh[(kg * 64 + w * 16 + lr) * 8];
        const bf16x8 bl = *(const bf16x8*)&Bl[(kg * 64 + w * 16 + lr) * 8];
#pragma unroll
        for (int r = 0; r < 4; ++r) {
            const bf16x8 ah = *(const bf16x8*)&Ah[(kg * 64 + r * 16 + lr) * 8];
            const bf16x8 al = *(const bf16x8*)&Al[(kg * 64 + r * 16 + lr) * 8];
            acc[r] = __builtin_amdgcn_mfma_f32_16x16x32_bf16(ah, bh, acc[r], 0, 0, 0);
            acc[r] = __builtin_amdgcn_mfma_f32_16x16x32_bf16(ah, bl, acc[r], 0, 0, 0);
            acc[r] = __builtin_amdgcn_mfma_f32_16x16x32_bf16(al, bh, acc[r], 0, 0, 0);
        }
        __syncthreads();
    }

    // epilogue: C/D layout col=lane&15, row=(lane>>4)*4+i  [m89]
    const int n = n0 + w * 16 + lr;
    if (n0 < D_INNER) {
#pragma unroll
        for (int r = 0; r < 4; ++r)
#pragma unroll
            for (int i = 0; i < 4; ++i) {
                const int t = m0 + r * 16 + kg * 4 + i;
                XP[t * D_INNER + n] = acc[r][i];
            }
    } else {
        const int n2 = n - D_INNER;
#pragma unroll
        for (int r = 0; r < 4; ++r)
#pragma unroll
            for (int i = 0; i < 4; ++i) {
                const int t = m0 + r * 16 + kg * 4 + i;
                const float c = acc[r][i];
                GT[n2 * NTOK + t] = c * sigmoidf_(c);
            }
    }
}

// ---------- generic tiled fp32 GEMM: C = A[M,K] * W[N,K]^T   (split-K via blockIdx.z)
// TRANSA: A passed as [K][M] with leading dim lda (time-major operands).
// MODE 0: plain store C[z*M*N + row*N+col].
// MODE 3: transposed store C[z*N*NTOK + col*NTOK+row].
// MODE 4: transposed store + softplus(acc+bias[col]).
template<int MODE, bool TRANSA>
__global__ __launch_bounds__(256, 2) void gemm_k(
    const float* __restrict__ A, int lda,
    const float* __restrict__ W,
    float* __restrict__ C,
    int M, int N, int K,
    const float* __restrict__ bias,
    float* __restrict__ C2,
    int kspan)
{
    __shared__ float As[16][68];   // [k][m]
    __shared__ float Ws[16][68];   // [k][n]
    const int tid = threadIdx.x;
    const int m0 = blockIdx.y * 64;
    const int n0 = blockIdx.x * 64;
    const int tx = tid & 15, ty = tid >> 4;
    const int lrow = tid >> 2;          // 0..63
    const int lk   = (tid & 3) << 2;    // 0,4,8,12
    const int kb   = blockIdx.z * kspan;
    const int ke   = (kb + kspan < K) ? (kb + kspan) : K;
    float acc[4][4] = {{0.f}};

    for (int k0 = kb; k0 < ke; k0 += 16) {
        if (TRANSA) {
            const int kk = k0 + (tid & 15);
            const int mq = tid >> 4;    // 0..15
            float4 v = make_float4(0.f, 0.f, 0.f, 0.f);
            if (kk < K) v = *(const float4*)&A[kk * lda + m0 + mq * 4];
            *(float4*)&As[tid & 15][mq * 4] = v;
        } else {
            const int m = m0 + lrow;
            const float* src = A + m * lda + (k0 + lk);
            float4 v = make_float4(0.f, 0.f, 0.f, 0.f);
            if (k0 + lk + 3 < K) v = *(const float4*)src;
            else {
                if (k0 + lk + 0 < K) v.x = src[0];
                if (k0 + lk + 1 < K) v.y = src[1];
                if (k0 + lk + 2 < K) v.z = src[2];
            }
            As[lk + 0][lrow] = v.x; As[lk + 1][lrow] = v.y;
            As[lk + 2][lrow] = v.z; As[lk + 3][lrow] = v.w;
        }
        {
            const int n = n0 + lrow;
            float4 u = make_float4(0.f, 0.f, 0.f, 0.f);
            if (n < N) {
                const float* srcw = W + n * K + (k0 + lk);
                if (k0 + lk + 3 < K) u = *(const float4*)srcw;
                else {
                    if (k0 + lk + 0 < K) u.x = srcw[0];
                    if (k0 + lk + 1 < K) u.y = srcw[1];
                    if (k0 + lk + 2 < K) u.z = srcw[2];
                }
            }
            Ws[lk + 0][lrow] = u.x; Ws[lk + 1][lrow] = u.y;
            Ws[lk + 2][lrow] = u.z; Ws[lk + 3][lrow] = u.w;
        }
        __syncthreads();
#pragma unroll
        for (int k = 0; k < 16; ++k) {
            float4 a4 = *(const float4*)&As[k][ty * 4];
            float4 w4 = *(const float4*)&Ws[k][tx * 4];
            float ar[4] = {a4.x, a4.y, a4.z, a4.w};
            float wr[4] = {w4.x, w4.y, w4.z, w4.w};
#pragma unroll
            for (int i = 0; i < 4; ++i)
#pragma unroll
                for (int j = 0; j < 4; ++j)
                    acc[i][j] = fmaf(ar[i], wr[j], acc[i][j]);
        }
        __syncthreads();
    }

    const int row0 = m0 + ty * 4;
    const int col0 = n0 + tx * 4;
    if (MODE == 0) {
        float* Cz = C + (size_t)blockIdx.z * M * N;
#pragma unroll
        for (int i = 0; i < 4; ++i) {
            float4 v = make_float4(acc[i][0], acc[i][1], acc[i][2], acc[i][3]);
            *(float4*)&Cz[(row0 + i) * N + col0] = v;
        }
    } else if (MODE == 3) {
        float* Cz = C + (size_t)blockIdx.z * N * NTOK;
#pragma unroll
        for (int j = 0; j < 4; ++j) {
            const int col = col0 + j;
            if (col < N) {
                float4 v = make_float4(acc[0][j], acc[1][j], acc[2][j], acc[3][j]);
                *(float4*)&Cz[col * NTOK + row0] = v;
            }
        }
    } else if (MODE == 4) {
#pragma unroll
        for (int j = 0; j < 4; ++j) {
            const int col = col0 + j;
            if (col < N) {
                const float bv = bias[col];
                float4 v = make_float4(softplusf_(acc[0][j] + bv), softplusf_(acc[1][j] + bv),
                                       softplusf_(acc[2][j] + bv), softplusf_(acc[3][j] + bv));
                *(float4*)&C[col * NTOK + row0] = v;
            }
        }
    }
}

// ---------- reduce split-K partials PX[8][56][2048] -> XDT[e][t]  (float4)
__global__ __launch_bounds__(256) void reduce_px_k(
    const float* __restrict__ PX, float* __restrict__ XDT)
{
    const int i4 = blockIdx.x * 256 + threadIdx.x;        // 28672 float4 elems
    float4 s = ((const float4*)PX)[i4];
#pragma unroll
    for (int z = 1; z < 8; ++z) {
        float4 v = ((const float4*)PX)[z * (XDIM * NTOK / 4) + i4];
        s.x += v.x; s.y += v.y; s.z += v.z; s.w += v.w;
    }
    ((float4*)XDT)[i4] = s;
}

// ---------- reduce split-K partials PO[4][2048][384] + scatter-accumulate into R
__global__ __launch_bounds__(384) void reduce_scatter_k(
    const float* __restrict__ PO, float* __restrict__ R, int order)
{
    const int m = blockIdx.x;
    const int col = threadIdx.x;
    float s = PO[m * D_MODEL + col];
#pragma unroll
    for (int z = 1; z < 4; ++z)
        s += PO[z * (NTOK * D_MODEL) + m * D_MODEL + col];
    const int tok = tok_of(order, m);
    R[tok * D_MODEL + col] += s;
}

// ---------- causal depthwise conv (k=4) + SiLU; XP[t][d] -> XCT[d][t]
__global__ __launch_bounds__(256) void conv_silu_t_k(
    const float* __restrict__ XP, const float* __restrict__ cw,
    const float* __restrict__ cb, float* __restrict__ XCT)
{
    __shared__ float xs[67][33];
    const int c0 = blockIdx.x * 32;
    const int t0 = blockIdx.y * 64;
    const int tid = threadIdx.x;
    const int col = tid & 31, rr = tid >> 5;
#pragma unroll
    for (int r = rr; r < 67; r += 8) {
        const int t = t0 - 3 + r;
        xs[r][col] = (t >= 0) ? XP[t * D_INNER + c0 + col] : 0.f;
    }
    __syncthreads();
    const int tl = tid & 63;
#pragma unroll
    for (int cl = tid >> 6; cl < 32; cl += 4) {
        const int c = c0 + cl;
        const float4 w4 = *(const float4*)(cw + c * 4);
        float acc = cb[c];
        acc = fmaf(w4.x, xs[tl + 0][cl], acc);
        acc = fmaf(w4.y, xs[tl + 1][cl], acc);
        acc = fmaf(w4.z, xs[tl + 2][cl], acc);
        acc = fmaf(w4.w, xs[tl + 3][cl], acc);
        XCT[c * NTOK + t0 + tl] = acc * sigmoidf_(acc);
    }
}

// ---------- chunked selective scan, phase 1: per-chunk (prod a, partial h) from h=0
__global__ __launch_bounds__(256) void scan_phase1_k(
    const float* __restrict__ XCT, const float* __restrict__ DTT,
    const float* __restrict__ XDT, const float* __restrict__ A_log,
    float* __restrict__ Aprod, float* __restrict__ Hpart)
{
    const int tid = threadIdx.x;
    const int s = tid & 15;
    const int d = blockIdx.x * 16 + (tid >> 4);
    const int chunk = blockIdx.y;
    const float Aneg = -expf(A_log[d * D_STATE + s]);
    const float* dtp = DTT + d * NTOK + chunk * CHUNK;
    const float* up  = XCT + d * NTOK + chunk * CHUNK;
    const float* Bp  = XDT + (DT_RANK + s) * NTOK + chunk * CHUNK;
    float h = 0.f, ap = 1.f;
#pragma unroll
    for (int tt = 0; tt < CHUNK; tt += 4) {
        const float4 dt4 = *(const float4*)(dtp + tt);
        const float4 u4  = *(const float4*)(up + tt);
        const float4 B4  = *(const float4*)(Bp + tt);
        float a;
        a = expf(dt4.x * Aneg); h = fmaf(a, h, dt4.x * B4.x * u4.x); ap *= a;
        a = expf(dt4.y * Aneg); h = fmaf(a, h, dt4.y * B4.y * u4.y); ap *= a;
        a = expf(dt4.z * Aneg); h = fmaf(a, h, dt4.z * B4.z * u4.z); ap *= a;
        a = expf(dt4.w * Aneg); h = fmaf(a, h, dt4.w * B4.w * u4.w); ap *= a;
    }
    const int idx = (chunk * D_INNER + d) * D_STATE + s;
    Aprod[idx] = ap;
    Hpart[idx] = h;
}

// ---------- phase 2: sequential scan over chunk summaries -> per-chunk initial h
__global__ __launch_bounds__(256) void scan_phase2_k(
    const float* __restrict__ Aprod, const float* __restrict__ Hpart,
    float* __restrict__ Hinit)
{
    const int tid = blockIdx.x * 256 + threadIdx.x;   // d*16+s, 12288 total
    float h = 0.f;
#pragma unroll 8
    for (int c = 0; c < NCHUNK; ++c) {
        const int idx = c * (D_INNER * D_STATE) + tid;
        Hinit[idx] = h;
        h = fmaf(Aprod[idx], h, Hpart[idx]);
    }
}

// ---------- phase 3: recompute within chunk from correct h0; fused u*D + gate
__global__ __launch_bounds__(256) void scan_phase3_k(
    const float* __restrict__ XCT, const float* __restrict__ DTT,
    const float* __restrict__ XDT, const float* __restrict__ GT,
    const float* __restrict__ A_log, const float* __restrict__ Dp,
    const float* __restrict__ Hinit, float* __restrict__ YGT)
{
    const int tid = threadIdx.x;
    const int s = tid & 15;
    const int d = blockIdx.x * 16 + (tid >> 4);
    const int chunk = blockIdx.y;
    const float Aneg = -expf(A_log[d * D_STATE + s]);
    const float Dv = Dp[d];
    const float* dtp = DTT + d * NTOK + chunk * CHUNK;
    const float* up  = XCT + d * NTOK + chunk * CHUNK;
    const float* Bp  = XDT + (DT_RANK + s) * NTOK + chunk * CHUNK;
    const float* Cp  = XDT + (DT_RANK + D_STATE + s) * NTOK + chunk * CHUNK;
    const float* Gp  = GT  + d * NTOK + chunk * CHUNK;
    float* Yp        = YGT + d * NTOK + chunk * CHUNK;
    float h = Hinit[(chunk * D_INNER + d) * D_STATE + s];
#pragma unroll
    for (int tt = 0; tt < CHUNK; tt += 4) {
        const float4 dt4 = *(const float4*)(dtp + tt);
        const float4 u4  = *(const float4*)(up + tt);
        const float4 B4  = *(const float4*)(Bp + tt);
        const float4 C4  = *(const float4*)(Cp + tt);
        float a, p0, p1, p2, p3;
        a = expf(dt4.x * Aneg); h = fmaf(a, h, dt4.x * B4.x * u4.x); p0 = h * C4.x;
        a = expf(dt4.y * Aneg); h = fmaf(a, h, dt4.y * B4.y * u4.y); p1 = h * C4.y;
        a = expf(dt4.z * Aneg); h = fmaf(a, h, dt4.z * B4.z * u4.z); p2 = h * C4.z;
        a = expf(dt4.w * Aneg); h = fmaf(a, h, dt4.w * B4.w * u4.w); p3 = h * C4.w;
#pragma unroll
        for (int m = 1; m <= 8; m <<= 1) {
            p0 += __shfl_xor(p0, m); p1 += __shfl_xor(p1, m);
            p2 += __shfl_xor(p2, m); p3 += __shfl_xor(p3, m);
        }
        if (s == 0) {
            const float4 g4 = *(const float4*)(Gp + tt);
            float4 y;
            y.x = (p0 + u4.x * Dv) * g4.x;
            y.y = (p1 + u4.y * Dv) * g4.y;
            y.z = (p2 + u4.z * Dv) * g4.z;
            y.w = (p3 + u4.w * Dv) * g4.w;
            *(float4*)(Yp + tt) = y;
        }
    }
}

extern "C" void kernel_launch(void* const* d_in, const int* in_sizes, int n_in,
                              void* d_out, int out_size, void* d_ws, size_t ws_size,
                              hipStream_t stream)
{
    const float* x        = (const float*)d_in[0];
    const float* norm_w   = (const float*)d_in[1];
    const float* in_proj  = (const float*)d_in[2];
    const float* conv_w   = (const float*)d_in[3];
    const float* conv_b   = (const float*)d_in[4];
    const float* x_proj   = (const float*)d_in[5];
    const float* dt_proj  = (const float*)d_in[6];
    const float* dt_b     = (const float*)d_in[7];
    const float* A_log    = (const float*)d_in[8];
    const float* D_param  = (const float*)d_in[9];
    const float* out_proj = (const float*)d_in[10];

    float* ws = (float*)d_ws;
    float* R     = ws;                     // 786432
    float* XP    = R   + 786432;           // 1572864 (aliases: PX first 917504; Hinit 786432 later)
    float* Xn    = XP  + 1572864;          // 786432  (alias: Aprod)
    float* GT    = Xn  + 786432;           // 1572864 ┐ PO = GT..XCT (3145728) after phase3
    float* XCT   = GT  + 1572864;          // 1572864 ┘
    float* XDT   = XCT + 1572864;          // 114688
    float* DTT   = XDT + 114688;           // 1572864
    float* YGT   = DTT + 1572864;          // 1572864 (alias: Hpart)
    float* Aprod = Xn;
    float* Hpart = YGT;
    float* Hinit = XP;
    float* PX    = XP;      // 8*56*2048 = 917504, live only conv-done -> reduce_px
    float* PO    = GT;      // 4*2048*384 = 3145728, live only after phase3

    hipMemcpyAsync(R, x, (size_t)786432 * sizeof(float), hipMemcpyDeviceToDevice, stream);

    for (int b = 0; b < 6; ++b) {
        rmsnorm_gather_k<<<NTOK, 128, 0, stream>>>(R, norm_w + b * D_MODEL, Xn, b);

        // in_proj via bf16x3 MFMA: -> XP[t][d] (xp half), GT[d][t]=silu(z half)
        inproj_mfma_k<<<dim3(24, 32), 256, 0, stream>>>(
            Xn, in_proj + (size_t)b * 2 * D_INNER * D_MODEL, XP, GT);

        conv_silu_t_k<<<dim3(24, 32), 256, 0, stream>>>(
            XP, conv_w + b * D_INNER * 4, conv_b + b * D_INNER, XCT);

        // x_proj split-K: (XCT^T)(2048x768) x W(56x768)^T -> PX[z][e][t], K=96/slice
        gemm_k<3, true><<<dim3(1, 32, 8), 256, 0, stream>>>(
            XCT, NTOK, x_proj + (size_t)b * XDIM * D_INNER, PX,
            NTOK, XDIM, D_INNER, nullptr, nullptr, 96);

        reduce_px_k<<<112, 256, 0, stream>>>(PX, XDT);

        // dt_proj: (XDT rows 0..23)^T (2048x24) x W(768x24)^T -> DTT[d][t] softplus+bias
        gemm_k<4, true><<<dim3(12, 32, 1), 256, 0, stream>>>(
            XDT, NTOK, dt_proj + (size_t)b * D_INNER * DT_RANK, DTT,
            NTOK, D_INNER, DT_RANK, dt_b + b * D_INNER, nullptr, DT_RANK);

        scan_phase1_k<<<dim3(48, NCHUNK), 256, 0, stream>>>(
            XCT, DTT, XDT, A_log + (size_t)b * D_INNER * D_STATE, Aprod, Hpart);

        scan_phase2_k<<<48, 256, 0, stream>>>(Aprod, Hpart, Hinit);

        scan_phase3_k<<<dim3(48, NCHUNK), 256, 0, stream>>>(
            XCT, DTT, XDT, GT, A_log + (size_t)b * D_INNER * D_STATE,
            D_param + b * D_INNER, Hinit, YGT);

        // out_proj split-K: (YGT^T)(2048x768) x W(384x768)^T -> PO[z][t][d], K=192/slice
        gemm_k<0, true><<<dim3(6, 32, 4), 256, 0, stream>>>(
            YGT, NTOK, out_proj + (size_t)b * D_MODEL * D_INNER, PO,
            NTOK, D_MODEL, D_INNER, nullptr, nullptr, 192);

        reduce_scatter_k<<<NTOK, 384, 0, stream>>>(PO, R, b);
    }

    hipMemcpyAsync(d_out, R, (size_t)786432 * sizeof(float), hipMemcpyDeviceToDevice, stream);
}

// Round 8
// 900.784 us; speedup vs baseline: 1.7883x; 1.0403x over previous
//
#include <hip/hip_runtime.h>
#include <math.h>

#define D_MODEL 384
#define D_INNER 768
#define D_STATE 16
#define DT_RANK 24
#define NTOK    2048
#define XDIM    56    // DT_RANK + 2*D_STATE
#define CHUNK   32
#define NCHUNK  (NTOK / CHUNK)   // 64

typedef __attribute__((ext_vector_type(8))) short bf16x8;
typedef __attribute__((ext_vector_type(4))) float f32x4;

// ---------- ordering maps: sequence position p -> canonical token (l*256+h*16+w)
__device__ __forceinline__ int tok_of(int order, int p) {
    int q = (order & 1) ? (NTOK - 1 - p) : p;
    int grp = order >> 1;          // 0: HWL, 1: LWH, 2: LHW (canonical)
    int l, h, w;
    if (grp == 0)      { h = q >> 7;  w = (q >> 3) & 15; l = q & 7;  }
    else if (grp == 1) { l = q >> 8;  w = (q >> 4) & 15; h = q & 15; }
    else               { return q; }
    return l * 256 + h * 16 + w;
}

__device__ __forceinline__ float sigmoidf_(float x) { return 1.f / (1.f + expf(-x)); }
__device__ __forceinline__ float softplusf_(float x) { return (x > 20.f) ? x : log1pf(expf(x)); }

// split fp32 -> bf16 hi (truncate) + bf16 lo (residual, truncate)
__device__ __forceinline__ void bf16split_(float a, unsigned short& hb, unsigned short& lb) {
    unsigned int ab = __float_as_uint(a);
    hb = (unsigned short)(ab >> 16);
    float hf = __uint_as_float(ab & 0xFFFF0000u);
    lb = (unsigned short)(__float_as_uint(a - hf) >> 16);
}

// ---------- pre-split a float array into bf16 hi/lo (float4-vectorized)
__global__ __launch_bounds__(256) void presplit_k(
    const float* __restrict__ A, unsigned short* __restrict__ H,
    unsigned short* __restrict__ L, int n4)
{
    const int i = blockIdx.x * 256 + threadIdx.x;
    if (i >= n4) return;
    const float4 v = ((const float4*)A)[i];
    ushort4 h, l;
    bf16split_(v.x, h.x, l.x);
    bf16split_(v.y, h.y, l.y);
    bf16split_(v.z, h.z, l.z);
    bf16split_(v.w, h.w, l.w);
    ((ushort4*)H)[i] = h;
    ((ushort4*)L)[i] = l;
}

// ---------- RMSNorm with gather; emits bf16 hi/lo directly
__global__ __launch_bounds__(128) void rmsnorm_gather_k(
    const float* __restrict__ R, const float* __restrict__ nw,
    unsigned short* __restrict__ Xnh, unsigned short* __restrict__ Xnl, int order)
{
    const int p   = blockIdx.x;
    const int tok = tok_of(order, p);
    const float* src = R + tok * D_MODEL;
    const int tid = threadIdx.x;
    float v0 = src[tid], v1 = src[tid + 128], v2 = src[tid + 256];
    float ss = v0 * v0 + v1 * v1 + v2 * v2;
#pragma unroll
    for (int off = 32; off > 0; off >>= 1) ss += __shfl_xor(ss, off);
    __shared__ float tot[2];
    if ((tid & 63) == 0) tot[tid >> 6] = ss;
    __syncthreads();
    const float rs = rsqrtf((tot[0] + tot[1]) * (1.f / D_MODEL) + 1e-5f);
    unsigned short h, l;
    bf16split_(v0 * rs * nw[tid], h, l);
    Xnh[p * D_MODEL + tid] = h;       Xnl[p * D_MODEL + tid] = l;
    bf16split_(v1 * rs * nw[tid + 128], h, l);
    Xnh[p * D_MODEL + tid + 128] = h; Xnl[p * D_MODEL + tid + 128] = l;
    bf16split_(v2 * rs * nw[tid + 256], h, l);
    Xnh[p * D_MODEL + tid + 256] = h; Xnl[p * D_MODEL + tid + 256] = l;
}

// ---------- in_proj via bf16x3 MFMA (pre-split operands): C = Xn[2048x384] * W[1536x384]^T
// n<768  -> XP[t*768+n] = c ; n>=768 -> GT[(n-768)*2048+t] = silu(c)
__global__ __launch_bounds__(256, 3) void inproj_mfma_k(
    const unsigned short* __restrict__ Ahg, const unsigned short* __restrict__ Alg,
    const unsigned short* __restrict__ WH, const unsigned short* __restrict__ WL,
    float* __restrict__ XP, float* __restrict__ GT)
{
    __shared__ __align__(16) short Ah[4 * 64 * 8];
    __shared__ __align__(16) short Al[4 * 64 * 8];
    __shared__ __align__(16) short Bh[4 * 64 * 8];
    __shared__ __align__(16) short Bl[4 * 64 * 8];

    const int tid = threadIdx.x;
    const int m0 = blockIdx.y * 64;
    const int n0 = blockIdx.x * 64;
    const int w  = tid >> 6;
    const int l  = tid & 63;
    const int lr = l & 15;
    const int kg = l >> 4;
    const int srow = tid >> 2;      // 0..63
    const int skq  = tid & 3;       // k-quarter

    f32x4 acc[4];
#pragma unroll
    for (int r = 0; r < 4; ++r) acc[r] = (f32x4){0.f, 0.f, 0.f, 0.f};

    for (int k0 = 0; k0 < D_MODEL; k0 += 32) {
        const int aoff = (m0 + srow) * D_MODEL + k0 + skq * 8;
        const int woff = (n0 + srow) * D_MODEL + k0 + skq * 8;
        const int soff = (skq * 64 + srow) * 8;
        *(bf16x8*)&Ah[soff] = *(const bf16x8*)&Ahg[aoff];
        *(bf16x8*)&Al[soff] = *(const bf16x8*)&Alg[aoff];
        *(bf16x8*)&Bh[soff] = *(const bf16x8*)&WH[woff];
        *(bf16x8*)&Bl[soff] = *(const bf16x8*)&WL[woff];
        __syncthreads();

        const bf16x8 bh = *(const bf16x8*)&Bh[(kg * 64 + w * 16 + lr) * 8];
        const bf16x8 bl = *(const bf16x8*)&Bl[(kg * 64 + w * 16 + lr) * 8];
#pragma unroll
        for (int r = 0; r < 4; ++r) {
            const bf16x8 ah = *(const bf16x8*)&Ah[(kg * 64 + r * 16 + lr) * 8];
            const bf16x8 al = *(const bf16x8*)&Al[(kg * 64 + r * 16 + lr) * 8];
            acc[r] = __builtin_amdgcn_mfma_f32_16x16x32_bf16(ah, bh, acc[r], 0, 0, 0);
            acc[r] = __builtin_amdgcn_mfma_f32_16x16x32_bf16(ah, bl, acc[r], 0, 0, 0);
            acc[r] = __builtin_amdgcn_mfma_f32_16x16x32_bf16(al, bh, acc[r], 0, 0, 0);
        }
        __syncthreads();
    }

    const int n = n0 + w * 16 + lr;
    if (n0 < D_INNER) {
#pragma unroll
        for (int r = 0; r < 4; ++r)
#pragma unroll
            for (int i = 0; i < 4; ++i) {
                const int t = m0 + r * 16 + kg * 4 + i;
                XP[t * D_INNER + n] = acc[r][i];
            }
    } else {
        const int n2 = n - D_INNER;
#pragma unroll
        for (int r = 0; r < 4; ++r)
#pragma unroll
            for (int i = 0; i < 4; ++i) {
                const int t = m0 + r * 16 + kg * 4 + i;
                const float c = acc[r][i];
                GT[n2 * NTOK + t] = c * sigmoidf_(c);
            }
    }
}

// ---------- out_proj via bf16x3 MFMA, split-K z=2: PO[z][t][col] = YG * W^T slice
__global__ __launch_bounds__(256, 3) void outproj_mfma_k(
    const float* __restrict__ YG, const unsigned short* __restrict__ WH,
    const unsigned short* __restrict__ WL, float* __restrict__ PO)
{
    __shared__ __align__(16) short Ah[4 * 64 * 8];
    __shared__ __align__(16) short Al[4 * 64 * 8];
    __shared__ __align__(16) short Bh[4 * 64 * 8];
    __shared__ __align__(16) short Bl[4 * 64 * 8];

    const int tid = threadIdx.x;
    const int m0 = blockIdx.y * 64;
    const int n0 = blockIdx.x * 64;
    const int kb = blockIdx.z * 384;
    const int w  = tid >> 6;
    const int l  = tid & 63;
    const int lr = l & 15;
    const int kg = l >> 4;
    const int srow = tid >> 2;
    const int skq  = tid & 3;

    f32x4 acc[4];
#pragma unroll
    for (int r = 0; r < 4; ++r) acc[r] = (f32x4){0.f, 0.f, 0.f, 0.f};

    for (int k0 = 0; k0 < 384; k0 += 32) {
        const float* ap = YG + (m0 + srow) * D_INNER + kb + k0 + skq * 8;
        const float4 a0 = *(const float4*)ap;
        const float4 a1 = *(const float4*)(ap + 4);
        const float av[8] = {a0.x, a0.y, a0.z, a0.w, a1.x, a1.y, a1.z, a1.w};
        union { bf16x8 v; unsigned short u[8]; } hu, lu;
#pragma unroll
        for (int j = 0; j < 8; ++j) bf16split_(av[j], hu.u[j], lu.u[j]);
        const int soff = (skq * 64 + srow) * 8;
        *(bf16x8*)&Ah[soff] = hu.v;
        *(bf16x8*)&Al[soff] = lu.v;
        const int woff = (n0 + srow) * D_INNER + kb + k0 + skq * 8;
        *(bf16x8*)&Bh[soff] = *(const bf16x8*)&WH[woff];
        *(bf16x8*)&Bl[soff] = *(const bf16x8*)&WL[woff];
        __syncthreads();

        const bf16x8 bh = *(const bf16x8*)&Bh[(kg * 64 + w * 16 + lr) * 8];
        const bf16x8 bl = *(const bf16x8*)&Bl[(kg * 64 + w * 16 + lr) * 8];
#pragma unroll
        for (int r = 0; r < 4; ++r) {
            const bf16x8 ah = *(const bf16x8*)&Ah[(kg * 64 + r * 16 + lr) * 8];
            const bf16x8 al = *(const bf16x8*)&Al[(kg * 64 + r * 16 + lr) * 8];
            acc[r] = __builtin_amdgcn_mfma_f32_16x16x32_bf16(ah, bh, acc[r], 0, 0, 0);
            acc[r] = __builtin_amdgcn_mfma_f32_16x16x32_bf16(ah, bl, acc[r], 0, 0, 0);
            acc[r] = __builtin_amdgcn_mfma_f32_16x16x32_bf16(al, bh, acc[r], 0, 0, 0);
        }
        __syncthreads();
    }

    float* Cz = PO + (size_t)blockIdx.z * NTOK * D_MODEL;
    const int n = n0 + w * 16 + lr;
#pragma unroll
    for (int r = 0; r < 4; ++r)
#pragma unroll
        for (int i = 0; i < 4; ++i) {
            const int t = m0 + r * 16 + kg * 4 + i;
            Cz[t * D_MODEL + n] = acc[r][i];
        }
}

// ---------- generic tiled fp32 GEMM (kept for x_proj / dt_proj)
// MODE 3: transposed store C[z*N*NTOK + col*NTOK+row]. MODE 4: + softplus(acc+bias).
template<int MODE, bool TRANSA>
__global__ __launch_bounds__(256, 2) void gemm_k(
    const float* __restrict__ A, int lda,
    const float* __restrict__ W,
    float* __restrict__ C,
    int M, int N, int K,
    const float* __restrict__ bias,
    float* __restrict__ C2,
    int kspan)
{
    __shared__ float As[16][68];
    __shared__ float Ws[16][68];
    const int tid = threadIdx.x;
    const int m0 = blockIdx.y * 64;
    const int n0 = blockIdx.x * 64;
    const int tx = tid & 15, ty = tid >> 4;
    const int lrow = tid >> 2;
    const int lk   = (tid & 3) << 2;
    const int kb   = blockIdx.z * kspan;
    const int ke   = (kb + kspan < K) ? (kb + kspan) : K;
    float acc[4][4] = {{0.f}};

    for (int k0 = kb; k0 < ke; k0 += 16) {
        if (TRANSA) {
            const int kk = k0 + (tid & 15);
            const int mq = tid >> 4;
            float4 v = make_float4(0.f, 0.f, 0.f, 0.f);
            if (kk < K) v = *(const float4*)&A[kk * lda + m0 + mq * 4];
            *(float4*)&As[tid & 15][mq * 4] = v;
        } else {
            const int m = m0 + lrow;
            const float* src = A + m * lda + (k0 + lk);
            float4 v = make_float4(0.f, 0.f, 0.f, 0.f);
            if (k0 + lk + 3 < K) v = *(const float4*)src;
            else {
                if (k0 + lk + 0 < K) v.x = src[0];
                if (k0 + lk + 1 < K) v.y = src[1];
                if (k0 + lk + 2 < K) v.z = src[2];
            }
            As[lk + 0][lrow] = v.x; As[lk + 1][lrow] = v.y;
            As[lk + 2][lrow] = v.z; As[lk + 3][lrow] = v.w;
        }
        {
            const int n = n0 + lrow;
            float4 u = make_float4(0.f, 0.f, 0.f, 0.f);
            if (n < N) {
                const float* srcw = W + n * K + (k0 + lk);
                if (k0 + lk + 3 < K) u = *(const float4*)srcw;
                else {
                    if (k0 + lk + 0 < K) u.x = srcw[0];
                    if (k0 + lk + 1 < K) u.y = srcw[1];
                    if (k0 + lk + 2 < K) u.z = srcw[2];
                }
            }
            Ws[lk + 0][lrow] = u.x; Ws[lk + 1][lrow] = u.y;
            Ws[lk + 2][lrow] = u.z; Ws[lk + 3][lrow] = u.w;
        }
        __syncthreads();
#pragma unroll
        for (int k = 0; k < 16; ++k) {
            float4 a4 = *(const float4*)&As[k][ty * 4];
            float4 w4 = *(const float4*)&Ws[k][tx * 4];
            float ar[4] = {a4.x, a4.y, a4.z, a4.w};
            float wr[4] = {w4.x, w4.y, w4.z, w4.w};
#pragma unroll
            for (int i = 0; i < 4; ++i)
#pragma unroll
                for (int j = 0; j < 4; ++j)
                    acc[i][j] = fmaf(ar[i], wr[j], acc[i][j]);
        }
        __syncthreads();
    }

    const int row0 = m0 + ty * 4;
    const int col0 = n0 + tx * 4;
    if (MODE == 3) {
        float* Cz = C + (size_t)blockIdx.z * N * NTOK;
#pragma unroll
        for (int j = 0; j < 4; ++j) {
            const int col = col0 + j;
            if (col < N) {
                float4 v = make_float4(acc[0][j], acc[1][j], acc[2][j], acc[3][j]);
                *(float4*)&Cz[col * NTOK + row0] = v;
            }
        }
    } else if (MODE == 4) {
#pragma unroll
        for (int j = 0; j < 4; ++j) {
            const int col = col0 + j;
            if (col < N) {
                const float bv = bias[col];
                float4 v = make_float4(softplusf_(acc[0][j] + bv), softplusf_(acc[1][j] + bv),
                                       softplusf_(acc[2][j] + bv), softplusf_(acc[3][j] + bv));
                *(float4*)&C[col * NTOK + row0] = v;
            }
        }
    }
}

// ---------- reduce split-K partials PX[8][56][2048] -> XDT[e][t]
__global__ __launch_bounds__(256) void reduce_px_k(
    const float* __restrict__ PX, float* __restrict__ XDT)
{
    const int i4 = blockIdx.x * 256 + threadIdx.x;
    float4 s = ((const float4*)PX)[i4];
#pragma unroll
    for (int z = 1; z < 8; ++z) {
        float4 v = ((const float4*)PX)[z * (XDIM * NTOK / 4) + i4];
        s.x += v.x; s.y += v.y; s.z += v.z; s.w += v.w;
    }
    ((float4*)XDT)[i4] = s;
}

// ---------- reduce split-K partials PO[2][2048][384] + scatter-accumulate into R
__global__ __launch_bounds__(384) void reduce_scatter_k(
    const float* __restrict__ PO, float* __restrict__ R, int order)
{
    const int m = blockIdx.x;
    const int col = threadIdx.x;
    float s = PO[m * D_MODEL + col] + PO[NTOK * D_MODEL + m * D_MODEL + col];
    const int tok = tok_of(order, m);
    R[tok * D_MODEL + col] += s;
}

// ---------- causal depthwise conv (k=4) + SiLU; XP[t][d] -> XCT[d][t]
__global__ __launch_bounds__(256) void conv_silu_t_k(
    const float* __restrict__ XP, const float* __restrict__ cw,
    const float* __restrict__ cb, float* __restrict__ XCT)
{
    __shared__ float xs[67][33];
    const int c0 = blockIdx.x * 32;
    const int t0 = blockIdx.y * 64;
    const int tid = threadIdx.x;
    const int col = tid & 31, rr = tid >> 5;
#pragma unroll
    for (int r = rr; r < 67; r += 8) {
        const int t = t0 - 3 + r;
        xs[r][col] = (t >= 0) ? XP[t * D_INNER + c0 + col] : 0.f;
    }
    __syncthreads();
    const int tl = tid & 63;
#pragma unroll
    for (int cl = tid >> 6; cl < 32; cl += 4) {
        const int c = c0 + cl;
        const float4 w4 = *(const float4*)(cw + c * 4);
        float acc = cb[c];
        acc = fmaf(w4.x, xs[tl + 0][cl], acc);
        acc = fmaf(w4.y, xs[tl + 1][cl], acc);
        acc = fmaf(w4.z, xs[tl + 2][cl], acc);
        acc = fmaf(w4.w, xs[tl + 3][cl], acc);
        XCT[c * NTOK + t0 + tl] = acc * sigmoidf_(acc);
    }
}

// ---------- chunked selective scan, phase 1
__global__ __launch_bounds__(256) void scan_phase1_k(
    const float* __restrict__ XCT, const float* __restrict__ DTT,
    const float* __restrict__ XDT, const float* __restrict__ A_log,
    float* __restrict__ Aprod, float* __restrict__ Hpart)
{
    const int tid = threadIdx.x;
    const int s = tid & 15;
    const int d = blockIdx.x * 16 + (tid >> 4);
    const int chunk = blockIdx.y;
    const float Aneg = -expf(A_log[d * D_STATE + s]);
    const float* dtp = DTT + d * NTOK + chunk * CHUNK;
    const float* up  = XCT + d * NTOK + chunk * CHUNK;
    const float* Bp  = XDT + (DT_RANK + s) * NTOK + chunk * CHUNK;
    float h = 0.f, ap = 1.f;
#pragma unroll
    for (int tt = 0; tt < CHUNK; tt += 4) {
        const float4 dt4 = *(const float4*)(dtp + tt);
        const float4 u4  = *(const float4*)(up + tt);
        const float4 B4  = *(const float4*)(Bp + tt);
        float a;
        a = expf(dt4.x * Aneg); h = fmaf(a, h, dt4.x * B4.x * u4.x); ap *= a;
        a = expf(dt4.y * Aneg); h = fmaf(a, h, dt4.y * B4.y * u4.y); ap *= a;
        a = expf(dt4.z * Aneg); h = fmaf(a, h, dt4.z * B4.z * u4.z); ap *= a;
        a = expf(dt4.w * Aneg); h = fmaf(a, h, dt4.w * B4.w * u4.w); ap *= a;
    }
    const int idx = (chunk * D_INNER + d) * D_STATE + s;
    Aprod[idx] = ap;
    Hpart[idx] = h;
}

// ---------- phase 2
__global__ __launch_bounds__(256) void scan_phase2_k(
    const float* __restrict__ Aprod, const float* __restrict__ Hpart,
    float* __restrict__ Hinit)
{
    const int tid = blockIdx.x * 256 + threadIdx.x;
    float h = 0.f;
#pragma unroll 8
    for (int c = 0; c < NCHUNK; ++c) {
        const int idx = c * (D_INNER * D_STATE) + tid;
        Hinit[idx] = h;
        h = fmaf(Aprod[idx], h, Hpart[idx]);
    }
}

// ---------- phase 3: recompute; fused u*D + gate; writes YG[t][d] (k-contig for out_proj)
__global__ __launch_bounds__(256) void scan_phase3_k(
    const float* __restrict__ XCT, const float* __restrict__ DTT,
    const float* __restrict__ XDT, const float* __restrict__ GT,
    const float* __restrict__ A_log, const float* __restrict__ Dp,
    const float* __restrict__ Hinit, float* __restrict__ YG)
{
    const int tid = threadIdx.x;
    const int s = tid & 15;
    const int d = blockIdx.x * 16 + (tid >> 4);
    const int chunk = blockIdx.y;
    const float Aneg = -expf(A_log[d * D_STATE + s]);
    const float Dv = Dp[d];
    const float* dtp = DTT + d * NTOK + chunk * CHUNK;
    const float* up  = XCT + d * NTOK + chunk * CHUNK;
    const float* Bp  = XDT + (DT_RANK + s) * NTOK + chunk * CHUNK;
    const float* Cp  = XDT + (DT_RANK + D_STATE + s) * NTOK + chunk * CHUNK;
    const float* Gp  = GT  + d * NTOK + chunk * CHUNK;
    float h = Hinit[(chunk * D_INNER + d) * D_STATE + s];
#pragma unroll
    for (int tt = 0; tt < CHUNK; tt += 4) {
        const float4 dt4 = *(const float4*)(dtp + tt);
        const float4 u4  = *(const float4*)(up + tt);
        const float4 B4  = *(const float4*)(Bp + tt);
        const float4 C4  = *(const float4*)(Cp + tt);
        float a, p0, p1, p2, p3;
        a = expf(dt4.x * Aneg); h = fmaf(a, h, dt4.x * B4.x * u4.x); p0 = h * C4.x;
        a = expf(dt4.y * Aneg); h = fmaf(a, h, dt4.y * B4.y * u4.y); p1 = h * C4.y;
        a = expf(dt4.z * Aneg); h = fmaf(a, h, dt4.z * B4.z * u4.z); p2 = h * C4.z;
        a = expf(dt4.w * Aneg); h = fmaf(a, h, dt4.w * B4.w * u4.w); p3 = h * C4.w;
#pragma unroll
        for (int m = 1; m <= 8; m <<= 1) {
            p0 += __shfl_xor(p0, m); p1 += __shfl_xor(p1, m);
            p2 += __shfl_xor(p2, m); p3 += __shfl_xor(p3, m);
        }
        if (s == 0) {
            const float4 g4 = *(const float4*)(Gp + tt);
            const int tbase = chunk * CHUNK + tt;
            YG[(tbase + 0) * D_INNER + d] = (p0 + u4.x * Dv) * g4.x;
            YG[(tbase + 1) * D_INNER + d] = (p1 + u4.y * Dv) * g4.y;
            YG[(tbase + 2) * D_INNER + d] = (p2 + u4.z * Dv) * g4.z;
            YG[(tbase + 3) * D_INNER + d] = (p3 + u4.w * Dv) * g4.w;
        }
    }
}

extern "C" void kernel_launch(void* const* d_in, const int* in_sizes, int n_in,
                              void* d_out, int out_size, void* d_ws, size_t ws_size,
                              hipStream_t stream)
{
    const float* x        = (const float*)d_in[0];
    const float* norm_w   = (const float*)d_in[1];
    const float* in_proj  = (const float*)d_in[2];
    const float* conv_w   = (const float*)d_in[3];
    const float* conv_b   = (const float*)d_in[4];
    const float* x_proj   = (const float*)d_in[5];
    const float* dt_proj  = (const float*)d_in[6];
    const float* dt_b     = (const float*)d_in[7];
    const float* A_log    = (const float*)d_in[8];
    const float* D_param  = (const float*)d_in[9];
    const float* out_proj = (const float*)d_in[10];

    float* ws = (float*)d_ws;
    float* R     = ws;                     // 786432
    float* XP    = R   + 786432;           // 1572864 (alias: PX 917504; Hinit 786432)
    float* XnHL  = XP  + 1572864;          // 786432  (Xnh 393216 + Xnl 393216; alias: Aprod)
    float* GT    = XnHL + 786432;          // 1572864 (alias: PO 1572864 after phase3)
    float* XCT   = GT  + 1572864;          // 1572864
    float* XDT   = XCT + 1572864;          // 114688
    float* DTT   = XDT + 114688;           // 1572864
    float* YG    = DTT + 1572864;          // 1572864 (alias: Hpart)
    float* WS1   = YG  + 1572864;          // weight splits below
    unsigned short* Xnh  = (unsigned short*)XnHL;
    unsigned short* Xnl  = Xnh + 786432;
    unsigned short* WinH = (unsigned short*)WS1;                 // 6*1536*384
    unsigned short* WinL = WinH + 6 * 1536 * 384;
    unsigned short* WoutH = WinL + 6 * 1536 * 384;               // 6*384*768
    unsigned short* WoutL = WoutH + 6 * 384 * 768;
    float* Aprod = XnHL;
    float* Hpart = YG;
    float* Hinit = XP;
    float* PX    = XP;
    float* PO    = GT;

    hipMemcpyAsync(R, x, (size_t)786432 * sizeof(float), hipMemcpyDeviceToDevice, stream);

    // pre-split weights (once per launch, identical work every call)
    presplit_k<<<(6 * 1536 * 384 / 4 + 255) / 256, 256, 0, stream>>>(
        in_proj, WinH, WinL, 6 * 1536 * 384 / 4);
    presplit_k<<<(6 * 384 * 768 / 4 + 255) / 256, 256, 0, stream>>>(
        out_proj, WoutH, WoutL, 6 * 384 * 768 / 4);

    for (int b = 0; b < 6; ++b) {
        rmsnorm_gather_k<<<NTOK, 128, 0, stream>>>(R, norm_w + b * D_MODEL, Xnh, Xnl, b);

        inproj_mfma_k<<<dim3(24, 32), 256, 0, stream>>>(
            Xnh, Xnl, WinH + (size_t)b * 1536 * 384, WinL + (size_t)b * 1536 * 384, XP, GT);

        conv_silu_t_k<<<dim3(24, 32), 256, 0, stream>>>(
            XP, conv_w + b * D_INNER * 4, conv_b + b * D_INNER, XCT);

        gemm_k<3, true><<<dim3(1, 32, 8), 256, 0, stream>>>(
            XCT, NTOK, x_proj + (size_t)b * XDIM * D_INNER, PX,
            NTOK, XDIM, D_INNER, nullptr, nullptr, 96);

        reduce_px_k<<<112, 256, 0, stream>>>(PX, XDT);

        gemm_k<4, true><<<dim3(12, 32, 1), 256, 0, stream>>>(
            XDT, NTOK, dt_proj + (size_t)b * D_INNER * DT_RANK, DTT,
            NTOK, D_INNER, DT_RANK, dt_b + b * D_INNER, nullptr, DT_RANK);

        scan_phase1_k<<<dim3(48, NCHUNK), 256, 0, stream>>>(
            XCT, DTT, XDT, A_log + (size_t)b * D_INNER * D_STATE, Aprod, Hpart);

        scan_phase2_k<<<48, 256, 0, stream>>>(Aprod, Hpart, Hinit);

        scan_phase3_k<<<dim3(48, NCHUNK), 256, 0, stream>>>(
            XCT, DTT, XDT, GT, A_log + (size_t)b * D_INNER * D_STATE,
            D_param + b * D_INNER, Hinit, YG);

        outproj_mfma_k<<<dim3(6, 32, 2), 256, 0, stream>>>(
            YG, WoutH + (size_t)b * 384 * 768, WoutL + (size_t)b * 384 * 768, PO);

        reduce_scatter_k<<<NTOK, 384, 0, stream>>>(PO, R, b);
    }

    hipMemcpyAsync(d_out, R, (size_t)786432 * sizeof(float), hipMemcpyDeviceToDevice, stream);
}

// Round 11
// 818.526 us; speedup vs baseline: 1.9680x; 1.1005x over previous
//
#include <hip/hip_runtime.h>
#include <math.h>

#define D_MODEL 384
#define D_INNER 768
#define D_STATE 16
#define DT_RANK 24
#define NTOK    2048
#define XDIM    56    // DT_RANK + 2*D_STATE
#define CHUNK   32
#define NCHUNK  (NTOK / CHUNK)   // 64

typedef __attribute__((ext_vector_type(8))) short bf16x8;
typedef __attribute__((ext_vector_type(4))) float f32x4;

// ---------- ordering maps: sequence position p -> canonical token (l*256+h*16+w)
__device__ __forceinline__ int tok_of(int order, int p) {
    int q = (order & 1) ? (NTOK - 1 - p) : p;
    int grp = order >> 1;          // 0: HWL, 1: LWH, 2: LHW (canonical)
    int l, h, w;
    if (grp == 0)      { h = q >> 7;  w = (q >> 3) & 15; l = q & 7;  }
    else if (grp == 1) { l = q >> 8;  w = (q >> 4) & 15; h = q & 15; }
    else               { return q; }
    return l * 256 + h * 16 + w;
}

__device__ __forceinline__ float sigmoidf_(float x) { return 1.f / (1.f + expf(-x)); }
__device__ __forceinline__ float softplusf_(float x) { return (x > 20.f) ? x : log1pf(expf(x)); }

// split fp32 -> bf16 hi (truncate) + bf16 lo (residual, truncate)
__device__ __forceinline__ void bf16split_(float a, unsigned short& hb, unsigned short& lb) {
    unsigned int ab = __float_as_uint(a);
    hb = (unsigned short)(ab >> 16);
    float hf = __uint_as_float(ab & 0xFFFF0000u);
    lb = (unsigned short)(__float_as_uint(a - hf) >> 16);
}

// ---------- pre-split a float array into bf16 hi/lo (float4-vectorized)
__global__ __launch_bounds__(256) void presplit_k(
    const float* __restrict__ A, unsigned short* __restrict__ H,
    unsigned short* __restrict__ L, int n4)
{
    const int i = blockIdx.x * 256 + threadIdx.x;
    if (i >= n4) return;
    const float4 v = ((const float4*)A)[i];
    ushort4 h, l;
    bf16split_(v.x, h.x, l.x);
    bf16split_(v.y, h.y, l.y);
    bf16split_(v.z, h.z, l.z);
    bf16split_(v.w, h.w, l.w);
    ((ushort4*)H)[i] = h;
    ((ushort4*)L)[i] = l;
}

// ---------- RMSNorm with gather; emits bf16 hi/lo directly
__global__ __launch_bounds__(128) void rmsnorm_gather_k(
    const float* __restrict__ R, const float* __restrict__ nw,
    unsigned short* __restrict__ Xnh, unsigned short* __restrict__ Xnl, int order)
{
    const int p   = blockIdx.x;
    const int tok = tok_of(order, p);
    const float* src = R + tok * D_MODEL;
    const int tid = threadIdx.x;
    float v0 = src[tid], v1 = src[tid + 128], v2 = src[tid + 256];
    float ss = v0 * v0 + v1 * v1 + v2 * v2;
#pragma unroll
    for (int off = 32; off > 0; off >>= 1) ss += __shfl_xor(ss, off);
    __shared__ float tot[2];
    if ((tid & 63) == 0) tot[tid >> 6] = ss;
    __syncthreads();
    const float rs = rsqrtf((tot[0] + tot[1]) * (1.f / D_MODEL) + 1e-5f);
    unsigned short h, l;
    bf16split_(v0 * rs * nw[tid], h, l);
    Xnh[p * D_MODEL + tid] = h;       Xnl[p * D_MODEL + tid] = l;
    bf16split_(v1 * rs * nw[tid + 128], h, l);
    Xnh[p * D_MODEL + tid + 128] = h; Xnl[p * D_MODEL + tid + 128] = l;
    bf16split_(v2 * rs * nw[tid + 256], h, l);
    Xnh[p * D_MODEL + tid + 256] = h; Xnl[p * D_MODEL + tid + 256] = l;
}

// ---------- in_proj via bf16x3 MFMA (pre-split operands): C = Xn[2048x384] * W[1536x384]^T
// n<768  -> XP[t*768+n] = c ; n>=768 -> GT[(n-768)*2048+t] = silu(c)
__global__ __launch_bounds__(256, 3) void inproj_mfma_k(
    const unsigned short* __restrict__ Ahg, const unsigned short* __restrict__ Alg,
    const unsigned short* __restrict__ WH, const unsigned short* __restrict__ WL,
    float* __restrict__ XP, float* __restrict__ GT)
{
    __shared__ __align__(16) short Ah[4 * 64 * 8];
    __shared__ __align__(16) short Al[4 * 64 * 8];
    __shared__ __align__(16) short Bh[4 * 64 * 8];
    __shared__ __align__(16) short Bl[4 * 64 * 8];

    const int tid = threadIdx.x;
    const int m0 = blockIdx.y * 64;
    const int n0 = blockIdx.x * 64;
    const int w  = tid >> 6;
    const int l  = tid & 63;
    const int lr = l & 15;
    const int kg = l >> 4;
    const int srow = tid >> 2;      // 0..63
    const int skq  = tid & 3;       // k-quarter

    f32x4 acc[4];
#pragma unroll
    for (int r = 0; r < 4; ++r) acc[r] = (f32x4){0.f, 0.f, 0.f, 0.f};

    for (int k0 = 0; k0 < D_MODEL; k0 += 32) {
        const int aoff = (m0 + srow) * D_MODEL + k0 + skq * 8;
        const int woff = (n0 + srow) * D_MODEL + k0 + skq * 8;
        const int soff = (skq * 64 + srow) * 8;
        *(bf16x8*)&Ah[soff] = *(const bf16x8*)&Ahg[aoff];
        *(bf16x8*)&Al[soff] = *(const bf16x8*)&Alg[aoff];
        *(bf16x8*)&Bh[soff] = *(const bf16x8*)&WH[woff];
        *(bf16x8*)&Bl[soff] = *(const bf16x8*)&WL[woff];
        __syncthreads();

        const bf16x8 bh = *(const bf16x8*)&Bh[(kg * 64 + w * 16 + lr) * 8];
        const bf16x8 bl = *(const bf16x8*)&Bl[(kg * 64 + w * 16 + lr) * 8];
#pragma unroll
        for (int r = 0; r < 4; ++r) {
            const bf16x8 ah = *(const bf16x8*)&Ah[(kg * 64 + r * 16 + lr) * 8];
            const bf16x8 al = *(const bf16x8*)&Al[(kg * 64 + r * 16 + lr) * 8];
            acc[r] = __builtin_amdgcn_mfma_f32_16x16x32_bf16(ah, bh, acc[r], 0, 0, 0);
            acc[r] = __builtin_amdgcn_mfma_f32_16x16x32_bf16(ah, bl, acc[r], 0, 0, 0);
            acc[r] = __builtin_amdgcn_mfma_f32_16x16x32_bf16(al, bh, acc[r], 0, 0, 0);
        }
        __syncthreads();
    }

    const int n = n0 + w * 16 + lr;
    if (n0 < D_INNER) {
#pragma unroll
        for (int r = 0; r < 4; ++r)
#pragma unroll
            for (int i = 0; i < 4; ++i) {
                const int t = m0 + r * 16 + kg * 4 + i;
                XP[t * D_INNER + n] = acc[r][i];
            }
    } else {
        const int n2 = n - D_INNER;
#pragma unroll
        for (int r = 0; r < 4; ++r)
#pragma unroll
            for (int i = 0; i < 4; ++i) {
                const int t = m0 + r * 16 + kg * 4 + i;
                const float c = acc[r][i];
                GT[n2 * NTOK + t] = c * sigmoidf_(c);
            }
    }
}

// ---------- out_proj via bf16x3 MFMA, split-K z=2: PO[z][t][col] = YG * W^T slice
__global__ __launch_bounds__(256, 3) void outproj_mfma_k(
    const float* __restrict__ YG, const unsigned short* __restrict__ WH,
    const unsigned short* __restrict__ WL, float* __restrict__ PO)
{
    __shared__ __align__(16) short Ah[4 * 64 * 8];
    __shared__ __align__(16) short Al[4 * 64 * 8];
    __shared__ __align__(16) short Bh[4 * 64 * 8];
    __shared__ __align__(16) short Bl[4 * 64 * 8];

    const int tid = threadIdx.x;
    const int m0 = blockIdx.y * 64;
    const int n0 = blockIdx.x * 64;
    const int kb = blockIdx.z * 384;
    const int w  = tid >> 6;
    const int l  = tid & 63;
    const int lr = l & 15;
    const int kg = l >> 4;
    const int srow = tid >> 2;
    const int skq  = tid & 3;

    f32x4 acc[4];
#pragma unroll
    for (int r = 0; r < 4; ++r) acc[r] = (f32x4){0.f, 0.f, 0.f, 0.f};

    for (int k0 = 0; k0 < 384; k0 += 32) {
        const float* ap = YG + (m0 + srow) * D_INNER + kb + k0 + skq * 8;
        const float4 a0 = *(const float4*)ap;
        const float4 a1 = *(const float4*)(ap + 4);
        const float av[8] = {a0.x, a0.y, a0.z, a0.w, a1.x, a1.y, a1.z, a1.w};
        union { bf16x8 v; unsigned short u[8]; } hu, lu;
#pragma unroll
        for (int j = 0; j < 8; ++j) bf16split_(av[j], hu.u[j], lu.u[j]);
        const int soff = (skq * 64 + srow) * 8;
        *(bf16x8*)&Ah[soff] = hu.v;
        *(bf16x8*)&Al[soff] = lu.v;
        const int woff = (n0 + srow) * D_INNER + kb + k0 + skq * 8;
        *(bf16x8*)&Bh[soff] = *(const bf16x8*)&WH[woff];
        *(bf16x8*)&Bl[soff] = *(const bf16x8*)&WL[woff];
        __syncthreads();

        const bf16x8 bh = *(const bf16x8*)&Bh[(kg * 64 + w * 16 + lr) * 8];
        const bf16x8 bl = *(const bf16x8*)&Bl[(kg * 64 + w * 16 + lr) * 8];
#pragma unroll
        for (int r = 0; r < 4; ++r) {
            const bf16x8 ah = *(const bf16x8*)&Ah[(kg * 64 + r * 16 + lr) * 8];
            const bf16x8 al = *(const bf16x8*)&Al[(kg * 64 + r * 16 + lr) * 8];
            acc[r] = __builtin_amdgcn_mfma_f32_16x16x32_bf16(ah, bh, acc[r], 0, 0, 0);
            acc[r] = __builtin_amdgcn_mfma_f32_16x16x32_bf16(ah, bl, acc[r], 0, 0, 0);
            acc[r] = __builtin_amdgcn_mfma_f32_16x16x32_bf16(al, bh, acc[r], 0, 0, 0);
        }
        __syncthreads();
    }

    float* Cz = PO + (size_t)blockIdx.z * NTOK * D_MODEL;
    const int n = n0 + w * 16 + lr;
#pragma unroll
    for (int r = 0; r < 4; ++r)
#pragma unroll
        for (int i = 0; i < 4; ++i) {
            const int t = m0 + r * 16 + kg * 4 + i;
            Cz[t * D_MODEL + n] = acc[r][i];
        }
}

// ---------- generic tiled fp32 GEMM (kept for x_proj / dt_proj)
// MODE 3: transposed store C[z*N*NTOK + col*NTOK+row]. MODE 4: + softplus(acc+bias).
template<int MODE, bool TRANSA>
__global__ __launch_bounds__(256, 2) void gemm_k(
    const float* __restrict__ A, int lda,
    const float* __restrict__ W,
    float* __restrict__ C,
    int M, int N, int K,
    const float* __restrict__ bias,
    float* __restrict__ C2,
    int kspan)
{
    __shared__ float As[16][68];
    __shared__ float Ws[16][68];
    const int tid = threadIdx.x;
    const int m0 = blockIdx.y * 64;
    const int n0 = blockIdx.x * 64;
    const int tx = tid & 15, ty = tid >> 4;
    const int lrow = tid >> 2;
    const int lk   = (tid & 3) << 2;
    const int kb   = blockIdx.z * kspan;
    const int ke   = (kb + kspan < K) ? (kb + kspan) : K;
    float acc[4][4] = {{0.f}};

    for (int k0 = kb; k0 < ke; k0 += 16) {
        if (TRANSA) {
            const int kk = k0 + (tid & 15);
            const int mq = tid >> 4;
            float4 v = make_float4(0.f, 0.f, 0.f, 0.f);
            if (kk < K) v = *(const float4*)&A[kk * lda + m0 + mq * 4];
            *(float4*)&As[tid & 15][mq * 4] = v;
        } else {
            const int m = m0 + lrow;
            const float* src = A + m * lda + (k0 + lk);
            float4 v = make_float4(0.f, 0.f, 0.f, 0.f);
            if (k0 + lk + 3 < K) v = *(const float4*)src;
            else {
                if (k0 + lk + 0 < K) v.x = src[0];
                if (k0 + lk + 1 < K) v.y = src[1];
                if (k0 + lk + 2 < K) v.z = src[2];
            }
            As[lk + 0][lrow] = v.x; As[lk + 1][lrow] = v.y;
            As[lk + 2][lrow] = v.z; As[lk + 3][lrow] = v.w;
        }
        {
            const int n = n0 + lrow;
            float4 u = make_float4(0.f, 0.f, 0.f, 0.f);
            if (n < N) {
                const float* srcw = W + n * K + (k0 + lk);
                if (k0 + lk + 3 < K) u = *(const float4*)srcw;
                else {
                    if (k0 + lk + 0 < K) u.x = srcw[0];
                    if (k0 + lk + 1 < K) u.y = srcw[1];
                    if (k0 + lk + 2 < K) u.z = srcw[2];
                }
            }
            Ws[lk + 0][lrow] = u.x; Ws[lk + 1][lrow] = u.y;
            Ws[lk + 2][lrow] = u.z; Ws[lk + 3][lrow] = u.w;
        }
        __syncthreads();
#pragma unroll
        for (int k = 0; k < 16; ++k) {
            float4 a4 = *(const float4*)&As[k][ty * 4];
            float4 w4 = *(const float4*)&Ws[k][tx * 4];
            float ar[4] = {a4.x, a4.y, a4.z, a4.w};
            float wr[4] = {w4.x, w4.y, w4.z, w4.w};
#pragma unroll
            for (int i = 0; i < 4; ++i)
#pragma unroll
                for (int j = 0; j < 4; ++j)
                    acc[i][j] = fmaf(ar[i], wr[j], acc[i][j]);
        }
        __syncthreads();
    }

    const int row0 = m0 + ty * 4;
    const int col0 = n0 + tx * 4;
    if (MODE == 3) {
        float* Cz = C + (size_t)blockIdx.z * N * NTOK;
#pragma unroll
        for (int j = 0; j < 4; ++j) {
            const int col = col0 + j;
            if (col < N) {
                float4 v = make_float4(acc[0][j], acc[1][j], acc[2][j], acc[3][j]);
                *(float4*)&Cz[col * NTOK + row0] = v;
            }
        }
    } else if (MODE == 4) {
#pragma unroll
        for (int j = 0; j < 4; ++j) {
            const int col = col0 + j;
            if (col < N) {
                const float bv = bias[col];
                float4 v = make_float4(softplusf_(acc[0][j] + bv), softplusf_(acc[1][j] + bv),
                                       softplusf_(acc[2][j] + bv), softplusf_(acc[3][j] + bv));
                *(float4*)&C[col * NTOK + row0] = v;
            }
        }
    }
}

// ---------- reduce split-K partials PX[8][56][2048] -> XDT[e][t]
__global__ __launch_bounds__(256) void reduce_px_k(
    const float* __restrict__ PX, float* __restrict__ XDT)
{
    const int i4 = blockIdx.x * 256 + threadIdx.x;
    float4 s = ((const float4*)PX)[i4];
#pragma unroll
    for (int z = 1; z < 8; ++z) {
        float4 v = ((const float4*)PX)[z * (XDIM * NTOK / 4) + i4];
        s.x += v.x; s.y += v.y; s.z += v.z; s.w += v.w;
    }
    ((float4*)XDT)[i4] = s;
}

// ---------- reduce split-K partials PO[2][2048][384] + scatter-accumulate into R
__global__ __launch_bounds__(384) void reduce_scatter_k(
    const float* __restrict__ PO, float* __restrict__ R, int order)
{
    const int m = blockIdx.x;
    const int col = threadIdx.x;
    float s = PO[m * D_MODEL + col] + PO[NTOK * D_MODEL + m * D_MODEL + col];
    const int tok = tok_of(order, m);
    R[tok * D_MODEL + col] += s;
}

// ---------- causal depthwise conv (k=4) + SiLU; XP[t][d] -> XCT[d][t]
__global__ __launch_bounds__(256) void conv_silu_t_k(
    const float* __restrict__ XP, const float* __restrict__ cw,
    const float* __restrict__ cb, float* __restrict__ XCT)
{
    __shared__ float xs[67][33];
    const int c0 = blockIdx.x * 32;
    const int t0 = blockIdx.y * 64;
    const int tid = threadIdx.x;
    const int col = tid & 31, rr = tid >> 5;
#pragma unroll
    for (int r = rr; r < 67; r += 8) {
        const int t = t0 - 3 + r;
        xs[r][col] = (t >= 0) ? XP[t * D_INNER + c0 + col] : 0.f;
    }
    __syncthreads();
    const int tl = tid & 63;
#pragma unroll
    for (int cl = tid >> 6; cl < 32; cl += 4) {
        const int c = c0 + cl;
        const float4 w4 = *(const float4*)(cw + c * 4);
        float acc = cb[c];
        acc = fmaf(w4.x, xs[tl + 0][cl], acc);
        acc = fmaf(w4.y, xs[tl + 1][cl], acc);
        acc = fmaf(w4.z, xs[tl + 2][cl], acc);
        acc = fmaf(w4.w, xs[tl + 3][cl], acc);
        XCT[c * NTOK + t0 + tl] = acc * sigmoidf_(acc);
    }
}

// ---------- chunked selective scan, phase 1: ILP=2 (two d-chains per thread)
__global__ __launch_bounds__(256) void scan_phase1_k(
    const float* __restrict__ XCT, const float* __restrict__ DTT,
    const float* __restrict__ XDT, const float* __restrict__ A_log,
    float* __restrict__ Aprod, float* __restrict__ Hpart)
{
    const int tid = threadIdx.x;
    const int s = tid & 15;
    const int d0 = blockIdx.x * 32 + (tid >> 4);
    const int d1 = d0 + 16;
    const int chunk = blockIdx.y;
    const float An0 = -expf(A_log[d0 * D_STATE + s]);
    const float An1 = -expf(A_log[d1 * D_STATE + s]);
    const float* dtp0 = DTT + d0 * NTOK + chunk * CHUNK;
    const float* dtp1 = DTT + d1 * NTOK + chunk * CHUNK;
    const float* up0  = XCT + d0 * NTOK + chunk * CHUNK;
    const float* up1  = XCT + d1 * NTOK + chunk * CHUNK;
    const float* Bp   = XDT + (DT_RANK + s) * NTOK + chunk * CHUNK;
    float h0 = 0.f, ap0 = 1.f, h1 = 0.f, ap1 = 1.f;
#pragma unroll
    for (int tt = 0; tt < CHUNK; tt += 4) {
        const float4 dA = *(const float4*)(dtp0 + tt);
        const float4 dB = *(const float4*)(dtp1 + tt);
        const float4 uA = *(const float4*)(up0 + tt);
        const float4 uB = *(const float4*)(up1 + tt);
        const float4 B4 = *(const float4*)(Bp + tt);
        float a0, a1;
        a0 = expf(dA.x * An0); a1 = expf(dB.x * An1);
        h0 = fmaf(a0, h0, dA.x * B4.x * uA.x); ap0 *= a0;
        h1 = fmaf(a1, h1, dB.x * B4.x * uB.x); ap1 *= a1;
        a0 = expf(dA.y * An0); a1 = expf(dB.y * An1);
        h0 = fmaf(a0, h0, dA.y * B4.y * uA.y); ap0 *= a0;
        h1 = fmaf(a1, h1, dB.y * B4.y * uB.y); ap1 *= a1;
        a0 = expf(dA.z * An0); a1 = expf(dB.z * An1);
        h0 = fmaf(a0, h0, dA.z * B4.z * uA.z); ap0 *= a0;
        h1 = fmaf(a1, h1, dB.z * B4.z * uB.z); ap1 *= a1;
        a0 = expf(dA.w * An0); a1 = expf(dB.w * An1);
        h0 = fmaf(a0, h0, dA.w * B4.w * uA.w); ap0 *= a0;
        h1 = fmaf(a1, h1, dB.w * B4.w * uB.w); ap1 *= a1;
    }
    const int idx0 = (chunk * D_INNER + d0) * D_STATE + s;
    const int idx1 = (chunk * D_INNER + d1) * D_STATE + s;
    Aprod[idx0] = ap0; Hpart[idx0] = h0;
    Aprod[idx1] = ap1; Hpart[idx1] = h1;
}

// ---------- phase 2
__global__ __launch_bounds__(256) void scan_phase2_k(
    const float* __restrict__ Aprod, const float* __restrict__ Hpart,
    float* __restrict__ Hinit)
{
    const int tid = blockIdx.x * 256 + threadIdx.x;
    float h = 0.f;
#pragma unroll 8
    for (int c = 0; c < NCHUNK; ++c) {
        const int idx = c * (D_INNER * D_STATE) + tid;
        Hinit[idx] = h;
        h = fmaf(Aprod[idx], h, Hpart[idx]);
    }
}

// ---------- phase 3: ILP=2; recompute; fused u*D + gate; writes YG[t][d]
__global__ __launch_bounds__(256) void scan_phase3_k(
    const float* __restrict__ XCT, const float* __restrict__ DTT,
    const float* __restrict__ XDT, const float* __restrict__ GT,
    const float* __restrict__ A_log, const float* __restrict__ Dp,
    const float* __restrict__ Hinit, float* __restrict__ YG)
{
    const int tid = threadIdx.x;
    const int s = tid & 15;
    const int d0 = blockIdx.x * 32 + (tid >> 4);
    const int d1 = d0 + 16;
    const int chunk = blockIdx.y;
    const float An0 = -expf(A_log[d0 * D_STATE + s]);
    const float An1 = -expf(A_log[d1 * D_STATE + s]);
    const float Dv0 = Dp[d0], Dv1 = Dp[d1];
    const float* dtp0 = DTT + d0 * NTOK + chunk * CHUNK;
    const float* dtp1 = DTT + d1 * NTOK + chunk * CHUNK;
    const float* up0  = XCT + d0 * NTOK + chunk * CHUNK;
    const float* up1  = XCT + d1 * NTOK + chunk * CHUNK;
    const float* Bp   = XDT + (DT_RANK + s) * NTOK + chunk * CHUNK;
    const float* Cp   = XDT + (DT_RANK + D_STATE + s) * NTOK + chunk * CHUNK;
    const float* Gp0  = GT  + d0 * NTOK + chunk * CHUNK;
    const float* Gp1  = GT  + d1 * NTOK + chunk * CHUNK;
    float h0 = Hinit[(chunk * D_INNER + d0) * D_STATE + s];
    float h1 = Hinit[(chunk * D_INNER + d1) * D_STATE + s];
#pragma unroll
    for (int tt = 0; tt < CHUNK; tt += 4) {
        const float4 dA = *(const float4*)(dtp0 + tt);
        const float4 dB = *(const float4*)(dtp1 + tt);
        const float4 uA = *(const float4*)(up0 + tt);
        const float4 uB = *(const float4*)(up1 + tt);
        const float4 B4 = *(const float4*)(Bp + tt);
        const float4 C4 = *(const float4*)(Cp + tt);
        float a0, a1;
        float p0A, p1A, p2A, p3A, p0B, p1B, p2B, p3B;
        a0 = expf(dA.x * An0); a1 = expf(dB.x * An1);
        h0 = fmaf(a0, h0, dA.x * B4.x * uA.x); p0A = h0 * C4.x;
        h1 = fmaf(a1, h1, dB.x * B4.x * uB.x); p0B = h1 * C4.x;
        a0 = expf(dA.y * An0); a1 = expf(dB.y * An1);
        h0 = fmaf(a0, h0, dA.y * B4.y * uA.y); p1A = h0 * C4.y;
        h1 = fmaf(a1, h1, dB.y * B4.y * uB.y); p1B = h1 * C4.y;
        a0 = expf(dA.z * An0); a1 = expf(dB.z * An1);
        h0 = fmaf(a0, h0, dA.z * B4.z * uA.z); p2A = h0 * C4.z;
        h1 = fmaf(a1, h1, dB.z * B4.z * uB.z); p2B = h1 * C4.z;
        a0 = expf(dA.w * An0); a1 = expf(dB.w * An1);
        h0 = fmaf(a0, h0, dA.w * B4.w * uA.w); p3A = h0 * C4.w;
        h1 = fmaf(a1, h1, dB.w * B4.w * uB.w); p3B = h1 * C4.w;
#pragma unroll
        for (int m = 1; m <= 8; m <<= 1) {
            p0A += __shfl_xor(p0A, m); p0B += __shfl_xor(p0B, m);
            p1A += __shfl_xor(p1A, m); p1B += __shfl_xor(p1B, m);
            p2A += __shfl_xor(p2A, m); p2B += __shfl_xor(p2B, m);
            p3A += __shfl_xor(p3A, m); p3B += __shfl_xor(p3B, m);
        }
        if (s == 0) {
            const float4 gA = *(const float4*)(Gp0 + tt);
            const float4 gB = *(const float4*)(Gp1 + tt);
            const int tbase = chunk * CHUNK + tt;
            YG[(tbase + 0) * D_INNER + d0] = (p0A + uA.x * Dv0) * gA.x;
            YG[(tbase + 1) * D_INNER + d0] = (p1A + uA.y * Dv0) * gA.y;
            YG[(tbase + 2) * D_INNER + d0] = (p2A + uA.z * Dv0) * gA.z;
            YG[(tbase + 3) * D_INNER + d0] = (p3A + uA.w * Dv0) * gA.w;
            YG[(tbase + 0) * D_INNER + d1] = (p0B + uB.x * Dv1) * gB.x;
            YG[(tbase + 1) * D_INNER + d1] = (p1B + uB.y * Dv1) * gB.y;
            YG[(tbase + 2) * D_INNER + d1] = (p2B + uB.z * Dv1) * gB.z;
            YG[(tbase + 3) * D_INNER + d1] = (p3B + uB.w * Dv1) * gB.w;
        }
    }
}

extern "C" void kernel_launch(void* const* d_in, const int* in_sizes, int n_in,
                              void* d_out, int out_size, void* d_ws, size_t ws_size,
                              hipStream_t stream)
{
    const float* x        = (const float*)d_in[0];
    const float* norm_w   = (const float*)d_in[1];
    const float* in_proj  = (const float*)d_in[2];
    const float* conv_w   = (const float*)d_in[3];
    const float* conv_b   = (const float*)d_in[4];
    const float* x_proj   = (const float*)d_in[5];
    const float* dt_proj  = (const float*)d_in[6];
    const float* dt_b     = (const float*)d_in[7];
    const float* A_log    = (const float*)d_in[8];
    const float* D_param  = (const float*)d_in[9];
    const float* out_proj = (const float*)d_in[10];

    float* ws = (float*)d_ws;
    float* R     = ws;                     // 786432
    float* XP    = R   + 786432;           // 1572864 (alias: PX 917504; Hinit 786432)
    float* XnHL  = XP  + 1572864;          // 786432  (Xnh 393216 + Xnl 393216; alias: Aprod)
    float* GT    = XnHL + 786432;          // 1572864 (alias: PO 1572864 after phase3)
    float* XCT   = GT  + 1572864;          // 1572864
    float* XDT   = XCT + 1572864;          // 114688
    float* DTT   = XDT + 114688;           // 1572864
    float* YG    = DTT + 1572864;          // 1572864 (alias: Hpart)
    float* WS1   = YG  + 1572864;          // weight splits below
    unsigned short* Xnh  = (unsigned short*)XnHL;
    unsigned short* Xnl  = Xnh + 786432;
    unsigned short* WinH = (unsigned short*)WS1;                 // 6*1536*384
    unsigned short* WinL = WinH + 6 * 1536 * 384;
    unsigned short* WoutH = WinL + 6 * 1536 * 384;               // 6*384*768
    unsigned short* WoutL = WoutH + 6 * 384 * 768;
    float* Aprod = XnHL;
    float* Hpart = YG;
    float* Hinit = XP;
    float* PX    = XP;
    float* PO    = GT;

    hipMemcpyAsync(R, x, (size_t)786432 * sizeof(float), hipMemcpyDeviceToDevice, stream);

    // pre-split weights (once per launch, identical work every call)
    presplit_k<<<(6 * 1536 * 384 / 4 + 255) / 256, 256, 0, stream>>>(
        in_proj, WinH, WinL, 6 * 1536 * 384 / 4);
    presplit_k<<<(6 * 384 * 768 / 4 + 255) / 256, 256, 0, stream>>>(
        out_proj, WoutH, WoutL, 6 * 384 * 768 / 4);

    for (int b = 0; b < 6; ++b) {
        rmsnorm_gather_k<<<NTOK, 128, 0, stream>>>(R, norm_w + b * D_MODEL, Xnh, Xnl, b);

        inproj_mfma_k<<<dim3(24, 32), 256, 0, stream>>>(
            Xnh, Xnl, WinH + (size_t)b * 1536 * 384, WinL + (size_t)b * 1536 * 384, XP, GT);

        conv_silu_t_k<<<dim3(24, 32), 256, 0, stream>>>(
            XP, conv_w + b * D_INNER * 4, conv_b + b * D_INNER, XCT);

        gemm_k<3, true><<<dim3(1, 32, 8), 256, 0, stream>>>(
            XCT, NTOK, x_proj + (size_t)b * XDIM * D_INNER, PX,
            NTOK, XDIM, D_INNER, nullptr, nullptr, 96);

        reduce_px_k<<<112, 256, 0, stream>>>(PX, XDT);

        gemm_k<4, true><<<dim3(12, 32, 1), 256, 0, stream>>>(
            XDT, NTOK, dt_proj + (size_t)b * D_INNER * DT_RANK, DTT,
            NTOK, D_INNER, DT_RANK, dt_b + b * D_INNER, nullptr, DT_RANK);

        scan_phase1_k<<<dim3(24, NCHUNK), 256, 0, stream>>>(
            XCT, DTT, XDT, A_log + (size_t)b * D_INNER * D_STATE, Aprod, Hpart);

        scan_phase2_k<<<48, 256, 0, stream>>>(Aprod, Hpart, Hinit);

        scan_phase3_k<<<dim3(24, NCHUNK), 256, 0, stream>>>(
            XCT, DTT, XDT, GT, A_log + (size_t)b * D_INNER * D_STATE,
            D_param + b * D_INNER, Hinit, YG);

        outproj_mfma_k<<<dim3(6, 32, 2), 256, 0, stream>>>(
            YG, WoutH + (size_t)b * 384 * 768, WoutL + (size_t)b * 384 * 768, PO);

        reduce_scatter_k<<<NTOK, 384, 0, stream>>>(PO, R, b);
    }

    hipMemcpyAsync(d_out, R, (size_t)786432 * sizeof(float), hipMemcpyDeviceToDevice, stream);
}